// Round 3
// baseline (377.850 us; speedup 1.0000x reference)
//
#include <hip/hip_runtime.h>
#include <hip/hip_bf16.h>

// Problem constants: B=2, C=512, H=W=64 -> N=4096, G=32 (16 ch/group), EPS=1e-6.

typedef float f32x4 __attribute__((ext_vector_type(4)));
typedef __bf16 bf16x8 __attribute__((ext_vector_type(8)));

typedef const __attribute__((address_space(1))) unsigned char* gas_p;
typedef __attribute__((address_space(3))) unsigned char* las_p;

__device__ __forceinline__ void gload_lds16(const void* g, void* l) {
  // async DMA: each lane contributes 16B; LDS dst = wave-uniform base + lane*16
  __builtin_amdgcn_global_load_lds((gas_p)g, (las_p)l, 16, 0, 0);
}

// ====== prelude: weight cvt (4x1024 blocks) | gn_stats (64) | bcat (1) ======
__global__ __launch_bounds__(256) void prelude_k(
    const float* __restrict__ wq, const float* __restrict__ wk,
    const float* __restrict__ wv, const float* __restrict__ wo,
    __hip_bfloat16* __restrict__ wqkb, __hip_bfloat16* __restrict__ wvb,
    __hip_bfloat16* __restrict__ wob, const float* __restrict__ bq,
    const float* __restrict__ bk, float* __restrict__ bqk,
    const float* __restrict__ x, float* __restrict__ stats) {
  int bid = blockIdx.x;
  if (bid < 4096) {
    const float* src;
    __hip_bfloat16* dst;
    if (bid < 1024)      { src = wq; dst = wqkb; }
    else if (bid < 2048) { src = wk; dst = wqkb + 262144; }
    else if (bid < 3072) { src = wv; dst = wvb; }
    else                 { src = wo; dst = wob; }
    int i = (bid & 1023) * 256 + threadIdx.x;  // 1024*256 = 262144 = 512*512
    dst[i] = __float2bfloat16(src[i]);
    return;
  }
  if (bid < 4160) {  // gn_stats: one block per (b,g)
    int bg = bid - 4096;
    const float4* p = (const float4*)(x + (size_t)bg * 65536);
    float s = 0.f, s2 = 0.f;
    for (int i = threadIdx.x; i < 16384; i += 256) {
      float4 v = p[i];
      s  += v.x + v.y + v.z + v.w;
      s2 += v.x * v.x + v.y * v.y + v.z * v.z + v.w * v.w;
    }
#pragma unroll
    for (int off = 32; off > 0; off >>= 1) {
      s  += __shfl_xor(s, off);
      s2 += __shfl_xor(s2, off);
    }
    __shared__ float rs[4], rs2[4];
    int wid = threadIdx.x >> 6, lane = threadIdx.x & 63;
    if (lane == 0) { rs[wid] = s; rs2[wid] = s2; }
    __syncthreads();
    if (threadIdx.x == 0) {
      float S  = rs[0] + rs[1] + rs[2] + rs[3];
      float S2 = rs2[0] + rs2[1] + rs2[2] + rs2[3];
      float mean = S * (1.f / 65536.f);
      float var  = S2 * (1.f / 65536.f) - mean * mean;
      stats[bg * 2]     = mean;
      stats[bg * 2 + 1] = rsqrtf(var + 1e-6f);
    }
    return;
  }
  // bcat
  for (int j = threadIdx.x; j < 1024; j += 256)
    bqk[j] = (j < 512) ? bq[j] : bk[j - 512];
}

// ------- GroupNorm apply + transpose, vectorized: x fp32 -> hf bf16 [b][n][c]
__global__ __launch_bounds__(256) void gn_apply_k(const float* __restrict__ x,
                                                  const float* __restrict__ stats,
                                                  const float* __restrict__ gw,
                                                  const float* __restrict__ gb,
                                                  __hip_bfloat16* __restrict__ hf) {
  int c0 = blockIdx.x * 64, n0 = blockIdx.y * 64, b = blockIdx.z;
  __shared__ float tile[64][65];
  int tid = threadIdx.x;
  int cl = tid >> 2, q = tid & 3;
  int c = c0 + cl;
  float mean = stats[(b * 32 + (c >> 4)) * 2];
  float rstd = stats[(b * 32 + (c >> 4)) * 2 + 1];
  float sc = rstd * gw[c];
  float sh = gb[c] - mean * sc;
  const float* xr = x + ((size_t)(b * 512 + c0 + cl)) * 4096 + n0 + q * 16;
#pragma unroll
  for (int j = 0; j < 4; j++) {
    float4 v = *(const float4*)(xr + 4 * j);
    int n = q * 16 + 4 * j;
    tile[cl][n]     = v.x * sc + sh;
    tile[cl][n + 1] = v.y * sc + sh;
    tile[cl][n + 2] = v.z * sc + sh;
    tile[cl][n + 3] = v.w * sc + sh;
  }
  __syncthreads();
  int nl = tid >> 2, ch = q * 16;
  bf16x8 o0, o1;
#pragma unroll
  for (int l = 0; l < 8; l++) {
    o0[l] = (__bf16)tile[ch + l][nl];
    o1[l] = (__bf16)tile[ch + 8 + l][nl];
  }
  __hip_bfloat16* op = hf + ((size_t)(b * 4096 + n0 + nl)) * 512 + c0 + ch;
  *(uint4*)op = *(uint4*)&o0;
  *(uint4*)(op + 8) = *(uint4*)&o1;
}

// ============ fused QKV (double-buffered DMA + LDS epilogue) ============
// bx<8 : QK GEMM  qk[t][o] (o<1024) = sum_c hf[t][c]*Wqk[o][c] + bqk[o]
// bx>=8: V GEMM   vT[b][o][t]       = sum_c Wv[o][c]*hf[t][c] + bv[o]
__global__ __launch_bounds__(256, 4) void qkv_k(
    const __hip_bfloat16* __restrict__ hf, const __hip_bfloat16* __restrict__ wqk,
    const __hip_bfloat16* __restrict__ wv, const float* __restrict__ bqk,
    const float* __restrict__ bv, __hip_bfloat16* __restrict__ qk,
    __hip_bfloat16* __restrict__ vT) {
  bool isV = blockIdx.x >= 8;
  int m0 = isV ? (blockIdx.x - 8) * 128 : blockIdx.y * 128;
  int n0 = isV ? blockIdx.y * 128 : blockIdx.x * 128;
  const __hip_bfloat16* A  = isV ? wv : hf;   // [m][512]
  const __hip_bfloat16* Bm = isV ? hf : wqk;  // [n][512]

  __shared__ __align__(16) unsigned char smem[34816];  // dbuf(32K) | epi(34K)
  __hip_bfloat16* As  = (__hip_bfloat16*)smem;
  __hip_bfloat16* Bs  = As + 8192;
  __hip_bfloat16* epi = (__hip_bfloat16*)smem;         // [128][136]

  int tid  = threadIdx.x;
  int wvx  = tid >> 6, lane = tid & 63;
  int wr   = (wvx >> 1) * 64, wc = (wvx & 1) * 64;
  int quad = lane >> 4, l16 = lane & 15;

  int srow = wvx * 32 + (lane >> 2);
  int scol = (lane & 3) * 8;
  const __hip_bfloat16* gA0 = A  + (size_t)(m0 + srow) * 512 + scol;
  const __hip_bfloat16* gA1 = gA0 + (size_t)16 * 512;
  const __hip_bfloat16* gB0 = Bm + (size_t)(n0 + srow) * 512 + scol;
  const __hip_bfloat16* gB1 = gB0 + (size_t)16 * 512;

  auto stage = [&](int kk, int bsel) {
    int lb = bsel * 4096 + wvx * 1024;
    gload_lds16(gA0 + kk, &As[lb]);
    gload_lds16(gA1 + kk, &As[lb + 512]);
    gload_lds16(gB0 + kk, &Bs[lb]);
    gload_lds16(gB1 + kk, &Bs[lb + 512]);
  };

  f32x4 acc[4][4] = {};
  stage(0, 0);
  for (int kt = 0; kt < 16; kt++) {
    __syncthreads();
    if (kt + 1 < 16) stage((kt + 1) << 5, (kt + 1) & 1);
    const __hip_bfloat16* Ab = &As[(kt & 1) * 4096];
    const __hip_bfloat16* Bb = &Bs[(kt & 1) * 4096];
    bf16x8 af[4], bfr[4];
#pragma unroll
    for (int i = 0; i < 4; i++)
      af[i] = *(const bf16x8*)&Ab[(wr + i * 16 + l16) * 32 + quad * 8];
#pragma unroll
    for (int j = 0; j < 4; j++)
      bfr[j] = *(const bf16x8*)&Bb[(wc + j * 16 + l16) * 32 + quad * 8];
#pragma unroll
    for (int i = 0; i < 4; i++)
#pragma unroll
      for (int j = 0; j < 4; j++)
        acc[i][j] = __builtin_amdgcn_mfma_f32_16x16x32_bf16(af[i], bfr[j],
                                                            acc[i][j], 0, 0, 0);
  }

  // ---- epilogue via LDS: C-layout -> row-major coalesced ----
  float bj[4], bm[4][4];
  if (!isV) {
#pragma unroll
    for (int j = 0; j < 4; j++) bj[j] = bqk[n0 + wc + j * 16 + l16];
  } else {
#pragma unroll
    for (int i = 0; i < 4; i++)
#pragma unroll
      for (int r = 0; r < 4; r++)
        bm[i][r] = bv[m0 + wr + i * 16 + quad * 4 + r];
  }
  __syncthreads();  // dbuf fragment reads done before epi overwrite
#pragma unroll
  for (int i = 0; i < 4; i++)
#pragma unroll
    for (int j = 0; j < 4; j++)
#pragma unroll
      for (int r = 0; r < 4; r++) {
        int ml = wr + i * 16 + quad * 4 + r;
        int nl = wc + j * 16 + l16;
        float v = acc[i][j][r] + (isV ? bm[i][r] : bj[j]);
        epi[ml * 136 + nl] = __float2bfloat16(v);
      }
  __syncthreads();
  int mr = tid >> 1, h = tid & 1;
  const __hip_bfloat16* rowp = &epi[mr * 136 + h * 64];
  if (!isV) {
    __hip_bfloat16* o = qk + (size_t)(m0 + mr) * 1024 + n0 + h * 64;
#pragma unroll
    for (int c = 0; c < 8; c++)
      *(uint4*)(o + c * 8) = *(const uint4*)(rowp + c * 8);
  } else {
    int b = (n0 + h * 64) >> 12, t = (n0 + h * 64) & 4095;
    __hip_bfloat16* o = vT + ((size_t)(b * 512 + m0 + mr)) * 4096 + t;
#pragma unroll
    for (int c = 0; c < 8; c++)
      *(uint4*)(o + c * 8) = *(const uint4*)(rowp + c * 8);
  }
}

// ====== fused attention v3: v1-proven body, kv-split 4, direct-global V =====
// Grid 512 = (2b x 4spl: one group per XCD) x 64 q-tiles(64 rows). 8 waves.
// LDS 67.6K -> 2 blocks/CU (cross-block overlap hides barrier drains).
// Per kv-tile 128: QK over d=512 in 8 dbuf BK=64 stages (v1's XOR-swizzled
// DMA), exp + reg rowsum -> Ps[64][136] (v1 layout), PV with V fragments read
// DIRECTLY from vT (L2-resident) -> 1 barrier per PV phase instead of 4.
// 80 barriers/block vs v1's 192.
__global__ __launch_bounds__(512, 2) void attn_k(
    const __hip_bfloat16* __restrict__ qk, const __hip_bfloat16* __restrict__ vT,
    __hip_bfloat16* __restrict__ part, float* __restrict__ rsum) {
  const float scale = 0.044194173824159216f;
  int bid = blockIdx.x;
  int g = bid & 7;
  int b = g >> 2, spl = g & 3;
  int qtile = bid >> 3;  // 0..63

  const __hip_bfloat16* qkb = qk + (size_t)b * 4194304;
  const __hip_bfloat16* vTb = vT + (size_t)b * 2097152;

  __shared__ __align__(16) unsigned char smem[67584];
  __hip_bfloat16* Qs = (__hip_bfloat16*)smem;             // 2 x [64][64]  16K
  __hip_bfloat16* Ks = (__hip_bfloat16*)(smem + 16384);   // 2 x [128][64] 32K
  __hip_bfloat16* Ps = (__hip_bfloat16*)(smem + 49152);   // [64][136]  17.4K
  float* Rs = (float*)(smem + 66560);                     // [4][64]      1K

  int tid = threadIdx.x, wv = tid >> 6, lane = tid & 63;
  int quad = lane >> 4, l16 = lane & 15;
  int q0 = (wv >> 2) * 32;    // wave q-rows (QK and PV)
  int kvc0 = (wv & 3) * 32;   // wave kv-cols (QK)
  int wd0 = (wv & 3) * 128;   // wave d-cols (PV)

  // staging: rows of 64 elems (128B), 8 rows/inst, XOR chunk swizzle
  // LDS[r][c] = G[r][c ^ (r&7)] (16B chunks) -> b128 frag reads spread banks
  int srow8 = lane >> 3;
  int schk = ((lane & 7) ^ srow8) * 8;
  const __hip_bfloat16* gQ =
      qkb + (size_t)(qtile * 64 + wv * 8 + srow8) * 1024 + schk;
  const __hip_bfloat16* gK0 =
      qkb + (size_t)(spl * 1024 + wv * 16 + srow8) * 1024 + 512 + schk;
  const __hip_bfloat16* gK1 = gK0 + (size_t)8 * 1024;

  auto stageQK = [&](int t, int s, int bsel) {
    int koff = t * 131072 + s * 64;  // t*128 rows + s*64 cols
    gload_lds16(gQ + s * 64, &Qs[bsel * 4096 + wv * 512]);
    gload_lds16(gK0 + koff, &Ks[bsel * 8192 + wv * 1024]);
    gload_lds16(gK1 + koff, &Ks[bsel * 8192 + wv * 1024 + 512]);
  };

  // per-lane V base: 16B fragments, rows stride 8KB; served by L1/L2
  const __hip_bfloat16* vbase =
      vTb + (size_t)(wd0 + l16) * 4096 + spl * 1024 + quad * 8;

  f32x4 accS[2][2] = {};
  f32x4 accO[8][2] = {};
  float rsr[8] = {};

  stageQK(0, 0, 0);
  for (int t = 0; t < 8; t++) {
    // ---- QK^T: accumulate S over d=512 in 8 BK=64 stages ----
    for (int s = 0; s < 8; s++) {
      __syncthreads();  // drains stage-s DMA; guards dbuf overwrite
      if (s < 7) stageQK(t, s + 1, (s + 1) & 1);
      const __hip_bfloat16* Qb = &Qs[(s & 1) * 4096];
      const __hip_bfloat16* Kb = &Ks[(s & 1) * 8192];
      bf16x8 aq[2][2], bkf[2][2];
#pragma unroll
      for (int ii = 0; ii < 2; ii++)
#pragma unroll
        for (int kk = 0; kk < 2; kk++) {
          int r = q0 + ii * 16 + l16;
          aq[ii][kk] = *(const bf16x8*)&Qb[r * 64 + ((kk * 4 + quad) ^ (r & 7)) * 8];
        }
#pragma unroll
      for (int jj = 0; jj < 2; jj++)
#pragma unroll
        for (int kk = 0; kk < 2; kk++) {
          int r = kvc0 + jj * 16 + l16;
          bkf[jj][kk] = *(const bf16x8*)&Kb[r * 64 + ((kk * 4 + quad) ^ (r & 7)) * 8];
        }
#pragma unroll
      for (int ii = 0; ii < 2; ii++)
#pragma unroll
        for (int jj = 0; jj < 2; jj++)
#pragma unroll
          for (int kk = 0; kk < 2; kk++)
            accS[ii][jj] = __builtin_amdgcn_mfma_f32_16x16x32_bf16(
                aq[ii][kk], bkf[jj][kk], accS[ii][jj], 0, 0, 0);
    }
    // ---- exp + rowsum, P -> LDS [64][136] (v1 layout, disjoint tiles) ----
#pragma unroll
    for (int ii = 0; ii < 2; ii++)
#pragma unroll
      for (int jj = 0; jj < 2; jj++) {
#pragma unroll
        for (int rr = 0; rr < 4; rr++) {
          float p = __expf(accS[ii][jj][rr] * scale);
          rsr[ii * 4 + rr] += p;
          Ps[(q0 + ii * 16 + quad * 4 + rr) * 136 + kvc0 + jj * 16 + l16] =
              __float2bfloat16(p);
        }
        accS[ii][jj] = (f32x4){0.f, 0.f, 0.f, 0.f};
      }
    __syncthreads();  // Ps visible to all waves
    if (t + 1 < 8) stageQK(t + 1, 0, 0);  // next tile stage-0; lands during PV
    // ---- PV: V fragments straight from L2; no inner barriers ----
    for (int sub = 0; sub < 4; sub++) {
      bf16x8 bvf[8];
      const __hip_bfloat16* vp = vbase + t * 128 + sub * 32;
#pragma unroll
      for (int jj = 0; jj < 8; jj++)
        bvf[jj] = *(const bf16x8*)(vp + jj * 65536);
      bf16x8 pa[2];
#pragma unroll
      for (int ii = 0; ii < 2; ii++)
        pa[ii] = *(const bf16x8*)&Ps[(q0 + ii * 16 + l16) * 136 + sub * 32 + quad * 8];
#pragma unroll
      for (int jj = 0; jj < 8; jj++)
#pragma unroll
        for (int ii = 0; ii < 2; ii++)
          accO[jj][ii] = __builtin_amdgcn_mfma_f32_16x16x32_bf16(
              pa[ii], bvf[jj], accO[jj][ii], 0, 0, 0);
    }
    __syncthreads();  // PV reads done before next-t Ps rewrite; drains prefetch
  }

  // ---- epilogue: partials (bf16) + per-row expsum ----
  size_t pbase = ((size_t)(spl * 2 + b) * 4096 + qtile * 64) * 512;
#pragma unroll
  for (int ii = 0; ii < 2; ii++)
#pragma unroll
    for (int rr = 0; rr < 4; rr++) {
      int row = q0 + ii * 16 + quad * 4 + rr;
#pragma unroll
      for (int jj = 0; jj < 8; jj++)
        part[pbase + (size_t)row * 512 + wd0 + jj * 16 + l16] =
            __float2bfloat16(accO[jj][ii][rr]);
    }
#pragma unroll
  for (int k = 0; k < 8; k++)
#pragma unroll
    for (int off = 1; off < 16; off <<= 1) rsr[k] += __shfl_xor(rsr[k], off);
  if (l16 == 0) {
#pragma unroll
    for (int ii = 0; ii < 2; ii++)
#pragma unroll
      for (int rr = 0; rr < 4; rr++)
        Rs[(wv & 3) * 64 + q0 + ii * 16 + quad * 4 + rr] = rsr[ii * 4 + rr];
  }
  __syncthreads();
  if (tid < 64)
    rsum[spl * 8192 + b * 4096 + qtile * 64 + tid] =
        Rs[tid] + Rs[64 + tid] + Rs[128 + tid] + Rs[192 + tid];
}

// ---- fold 4 kv-split partials + expsums, normalize -> obuf ----
__global__ __launch_bounds__(256) void reduce2_k(
    const __hip_bfloat16* __restrict__ part, const float* __restrict__ rsum,
    __hip_bfloat16* __restrict__ obuf) {
  size_t i8 = (size_t)blockIdx.x * 256 + threadIdx.x;
  size_t perb = 262144;  // 4096*512/8 vectors per batch
  size_t b = i8 / perb, r = i8 - b * perb;
  int t = (int)(r >> 6);
  float ps = rsum[b * 4096 + t] + rsum[8192 + b * 4096 + t] +
             rsum[16384 + b * 4096 + t] + rsum[24576 + b * 4096 + t];
  float inv = 1.f / ps;
  float acc[8] = {};
#pragma unroll
  for (int sp = 0; sp < 4; sp++) {
    bf16x8 v = ((const bf16x8*)part)[(sp * 2 + b) * perb + r];
#pragma unroll
    for (int l = 0; l < 8; l++) acc[l] += (float)v[l];
  }
  bf16x8 o;
#pragma unroll
  for (int l = 0; l < 8; l++) o[l] = (__bf16)(acc[l] * inv);
  ((bf16x8*)obuf)[b * perb + r] = o;
}

// ====== out-proj, 64x128 tiles (512 blocks = 2/CU vs old 256 = 1/CU) ======
// out[b][c][t] = x[b][c][t] + bf16(sum_o Wo[c][o]*obuf[b][t][o] + bo[c])
__global__ __launch_bounds__(256, 2) void oproj_k(
    const __hip_bfloat16* __restrict__ Wo, const __hip_bfloat16* __restrict__ O,
    float* __restrict__ out, const float* __restrict__ bias,
    const float* __restrict__ resid) {
  int m0 = blockIdx.y * 64, n0 = blockIdx.x * 128, bb = blockIdx.z;
  O += (size_t)bb * 4096 * 512;
  size_t cbase = (size_t)bb * 512 * 4096;

  __shared__ __align__(16) unsigned char smem[24576];  // A 2x4K | B 2x8K; epi
  __hip_bfloat16* As  = (__hip_bfloat16*)smem;          // 2 x [64][32]
  __hip_bfloat16* Bs  = As + 4096;                      // 2 x [128][32]
  __hip_bfloat16* epi = (__hip_bfloat16*)smem;          // [64][136] = 17.4K

  int tid = threadIdx.x, wv = tid >> 6, lane = tid & 63;
  int wr = (wv >> 1) * 32, wc = (wv & 1) * 64;
  int quad = lane >> 4, l16 = lane & 15;

  int lr = lane >> 2, scol = (lane & 3) * 8;
  const __hip_bfloat16* gA  = Wo + (size_t)(m0 + wv * 16 + lr) * 512 + scol;
  const __hip_bfloat16* gB0 = O  + (size_t)(n0 + wv * 32 + lr) * 512 + scol;
  const __hip_bfloat16* gB1 = gB0 + (size_t)16 * 512;

  auto stage = [&](int kk, int bsel) {
    gload_lds16(gA + kk, &As[bsel * 2048 + wv * 512]);
    gload_lds16(gB0 + kk, &Bs[bsel * 4096 + wv * 1024]);
    gload_lds16(gB1 + kk, &Bs[bsel * 4096 + wv * 1024 + 512]);
  };

  f32x4 acc[2][4] = {};
  stage(0, 0);
  for (int kt = 0; kt < 16; kt++) {
    __syncthreads();
    if (kt + 1 < 16) stage((kt + 1) << 5, (kt + 1) & 1);
    const __hip_bfloat16* Ab = &As[(kt & 1) * 2048];
    const __hip_bfloat16* Bb = &Bs[(kt & 1) * 4096];
    bf16x8 af[2], bfr[4];
#pragma unroll
    for (int i = 0; i < 2; i++)
      af[i] = *(const bf16x8*)&Ab[(wr + i * 16 + l16) * 32 + quad * 8];
#pragma unroll
    for (int j = 0; j < 4; j++)
      bfr[j] = *(const bf16x8*)&Bb[(wc + j * 16 + l16) * 32 + quad * 8];
#pragma unroll
    for (int i = 0; i < 2; i++)
#pragma unroll
      for (int j = 0; j < 4; j++)
        acc[i][j] = __builtin_amdgcn_mfma_f32_16x16x32_bf16(af[i], bfr[j],
                                                            acc[i][j], 0, 0, 0);
  }

  float pre[2][4];
#pragma unroll
  for (int i = 0; i < 2; i++)
#pragma unroll
    for (int r = 0; r < 4; r++)
      pre[i][r] = bias[m0 + wr + i * 16 + quad * 4 + r];
  __syncthreads();
#pragma unroll
  for (int i = 0; i < 2; i++)
#pragma unroll
    for (int j = 0; j < 4; j++)
#pragma unroll
      for (int r = 0; r < 4; r++)
        epi[(wr + i * 16 + quad * 4 + r) * 136 + wc + j * 16 + l16] =
            __float2bfloat16(acc[i][j][r] + pre[i][r]);
  __syncthreads();
  int mr = tid >> 2, seg = tid & 3;  // 4 threads/row, 32 elems each
  const __hip_bfloat16* rowp = &epi[mr * 136 + seg * 32];
  size_t obase = cbase + (size_t)(m0 + mr) * 4096 + n0 + seg * 32;
#pragma unroll
  for (int c = 0; c < 4; c++) {
    bf16x8 val = *(const bf16x8*)(rowp + c * 8);
    size_t idx = obase + c * 8;
    float4 r0 = *(const float4*)&resid[idx];
    float4 r1 = *(const float4*)&resid[idx + 4];
    float4 o0, o1;
    o0.x = r0.x + (float)val[0]; o0.y = r0.y + (float)val[1];
    o0.z = r0.z + (float)val[2]; o0.w = r0.w + (float)val[3];
    o1.x = r1.x + (float)val[4]; o1.y = r1.y + (float)val[5];
    o1.z = r1.z + (float)val[6]; o1.w = r1.w + (float)val[7];
    *(float4*)&out[idx] = o0;
    *(float4*)&out[idx + 4] = o1;
  }
}

extern "C" void kernel_launch(void* const* d_in, const int* in_sizes, int n_in,
                              void* d_out, int out_size, void* d_ws,
                              size_t ws_size, hipStream_t stream) {
  const float* xp  = (const float*)d_in[0];
  const float* gwp = (const float*)d_in[1];
  const float* gbp = (const float*)d_in[2];
  const float* wqp = (const float*)d_in[3];
  const float* bqp = (const float*)d_in[4];
  const float* wkp = (const float*)d_in[5];
  const float* bkp = (const float*)d_in[6];
  const float* wvp = (const float*)d_in[7];
  const float* bvp = (const float*)d_in[8];
  const float* wop = (const float*)d_in[9];
  const float* bop = (const float*)d_in[10];
  float* outp = (float*)d_out;

  char* w = (char*)d_ws;
  size_t off = 0;
  auto alloc = [&](size_t bytes) {
    void* p = w + off;
    off += (bytes + 255) & ~(size_t)255;
    return p;
  };
  float* stats         = (float*)alloc(64 * 2 * sizeof(float));
  __hip_bfloat16* hf   = (__hip_bfloat16*)alloc((size_t)2 * 4096 * 512 * 2);
  __hip_bfloat16* wqkb = (__hip_bfloat16*)alloc((size_t)1024 * 512 * 2);
  __hip_bfloat16* wvb  = (__hip_bfloat16*)alloc((size_t)512 * 512 * 2);
  __hip_bfloat16* wob  = (__hip_bfloat16*)alloc((size_t)512 * 512 * 2);
  float* bqk           = (float*)alloc(1024 * sizeof(float));
  float* rsum          = (float*)alloc((size_t)4 * 2 * 4096 * sizeof(float));
  __hip_bfloat16* qk   = (__hip_bfloat16*)alloc((size_t)2 * 4096 * 1024 * 2);
  __hip_bfloat16* vT   = (__hip_bfloat16*)alloc((size_t)2 * 512 * 4096 * 2);
  __hip_bfloat16* obuf = (__hip_bfloat16*)alloc((size_t)2 * 4096 * 512 * 2);
  __hip_bfloat16* part = (__hip_bfloat16*)alloc((size_t)8 * 4096 * 512 * 2);

  // prelude: 4096 cvt blocks + 64 gn_stats blocks + 1 bcat block
  prelude_k<<<4161, 256, 0, stream>>>(wqp, wkp, wvp, wop, wqkb, wvb, wob,
                                      bqp, bkp, bqk, xp, stats);

  gn_apply_k<<<dim3(8, 64, 2), 256, 0, stream>>>(xp, stats, gwp, gbp, hf);

  // fused QKV: qk[8192][1024] and vT[2][512][4096]
  qkv_k<<<dim3(12, 64, 1), 256, 0, stream>>>(hf, wqkb, wvb, bqk, bvp, qk, vT);

  // fused attention v3: 512 blocks (2/CU), kv-split 4, S never hits HBM
  attn_k<<<512, 512, 0, stream>>>(qk, vT, part, rsum);

  // fold 4 partials + expsums, normalize -> obuf
  reduce2_k<<<2048, 256, 0, stream>>>(part, rsum, obuf);

  // out[b][c][t] = x + Wo*O + bo  (64x128 tiles, 512 blocks)
  oproj_k<<<dim3(32, 8, 2), 256, 0, stream>>>(wob, obuf, outp, bop, xp);
}

// Round 4
// 333.124 us; speedup vs baseline: 1.1343x; 1.1343x over previous
//
#include <hip/hip_runtime.h>
#include <hip/hip_bf16.h>

// Problem constants: B=2, C=512, H=W=64 -> N=4096, G=32 (16 ch/group), EPS=1e-6.

typedef float f32x4 __attribute__((ext_vector_type(4)));
typedef __bf16 bf16x8 __attribute__((ext_vector_type(8)));

typedef const __attribute__((address_space(1))) unsigned char* gas_p;
typedef __attribute__((address_space(3))) unsigned char* las_p;

__device__ __forceinline__ void gload_lds16(const void* g, void* l) {
  // async DMA: each lane contributes 16B; LDS dst = wave-uniform base + lane*16
  __builtin_amdgcn_global_load_lds((gas_p)g, (las_p)l, 16, 0, 0);
}

// ====== prelude: weight cvt (4x1024 blocks) | gn_stats (64) | bcat (1) ======
__global__ __launch_bounds__(256) void prelude_k(
    const float* __restrict__ wq, const float* __restrict__ wk,
    const float* __restrict__ wv, const float* __restrict__ wo,
    __hip_bfloat16* __restrict__ wqkb, __hip_bfloat16* __restrict__ wvb,
    __hip_bfloat16* __restrict__ wob, const float* __restrict__ bq,
    const float* __restrict__ bk, float* __restrict__ bqk,
    const float* __restrict__ x, float* __restrict__ stats) {
  int bid = blockIdx.x;
  if (bid < 4096) {
    const float* src;
    __hip_bfloat16* dst;
    if (bid < 1024)      { src = wq; dst = wqkb; }
    else if (bid < 2048) { src = wk; dst = wqkb + 262144; }
    else if (bid < 3072) { src = wv; dst = wvb; }
    else                 { src = wo; dst = wob; }
    int i = (bid & 1023) * 256 + threadIdx.x;  // 1024*256 = 262144 = 512*512
    dst[i] = __float2bfloat16(src[i]);
    return;
  }
  if (bid < 4160) {  // gn_stats: one block per (b,g)
    int bg = bid - 4096;
    const float4* p = (const float4*)(x + (size_t)bg * 65536);
    float s = 0.f, s2 = 0.f;
    for (int i = threadIdx.x; i < 16384; i += 256) {
      float4 v = p[i];
      s  += v.x + v.y + v.z + v.w;
      s2 += v.x * v.x + v.y * v.y + v.z * v.z + v.w * v.w;
    }
#pragma unroll
    for (int off = 32; off > 0; off >>= 1) {
      s  += __shfl_xor(s, off);
      s2 += __shfl_xor(s2, off);
    }
    __shared__ float rs[4], rs2[4];
    int wid = threadIdx.x >> 6, lane = threadIdx.x & 63;
    if (lane == 0) { rs[wid] = s; rs2[wid] = s2; }
    __syncthreads();
    if (threadIdx.x == 0) {
      float S  = rs[0] + rs[1] + rs[2] + rs[3];
      float S2 = rs2[0] + rs2[1] + rs2[2] + rs2[3];
      float mean = S * (1.f / 65536.f);
      float var  = S2 * (1.f / 65536.f) - mean * mean;
      stats[bg * 2]     = mean;
      stats[bg * 2 + 1] = rsqrtf(var + 1e-6f);
    }
    return;
  }
  // bcat
  for (int j = threadIdx.x; j < 1024; j += 256)
    bqk[j] = (j < 512) ? bq[j] : bk[j - 512];
}

// ------- GroupNorm apply + transpose, vectorized: x fp32 -> hf bf16 [b][n][c]
__global__ __launch_bounds__(256) void gn_apply_k(const float* __restrict__ x,
                                                  const float* __restrict__ stats,
                                                  const float* __restrict__ gw,
                                                  const float* __restrict__ gb,
                                                  __hip_bfloat16* __restrict__ hf) {
  int c0 = blockIdx.x * 64, n0 = blockIdx.y * 64, b = blockIdx.z;
  __shared__ float tile[64][65];
  int tid = threadIdx.x;
  int cl = tid >> 2, q = tid & 3;
  int c = c0 + cl;
  float mean = stats[(b * 32 + (c >> 4)) * 2];
  float rstd = stats[(b * 32 + (c >> 4)) * 2 + 1];
  float sc = rstd * gw[c];
  float sh = gb[c] - mean * sc;
  const float* xr = x + ((size_t)(b * 512 + c0 + cl)) * 4096 + n0 + q * 16;
#pragma unroll
  for (int j = 0; j < 4; j++) {
    float4 v = *(const float4*)(xr + 4 * j);
    int n = q * 16 + 4 * j;
    tile[cl][n]     = v.x * sc + sh;
    tile[cl][n + 1] = v.y * sc + sh;
    tile[cl][n + 2] = v.z * sc + sh;
    tile[cl][n + 3] = v.w * sc + sh;
  }
  __syncthreads();
  int nl = tid >> 2, ch = q * 16;
  bf16x8 o0, o1;
#pragma unroll
  for (int l = 0; l < 8; l++) {
    o0[l] = (__bf16)tile[ch + l][nl];
    o1[l] = (__bf16)tile[ch + 8 + l][nl];
  }
  __hip_bfloat16* op = hf + ((size_t)(b * 4096 + n0 + nl)) * 512 + c0 + ch;
  *(uint4*)op = *(uint4*)&o0;
  *(uint4*)(op + 8) = *(uint4*)&o1;
}

// ============ fused QKV (double-buffered DMA + LDS epilogue) ============
// bx<8 : QK GEMM  qk[t][o] (o<1024) = sum_c hf[t][c]*Wqk[o][c] + bqk[o]
// bx>=8: V GEMM   vT[b][o][t]       = sum_c Wv[o][c]*hf[t][c] + bv[o]
__global__ __launch_bounds__(256, 4) void qkv_k(
    const __hip_bfloat16* __restrict__ hf, const __hip_bfloat16* __restrict__ wqk,
    const __hip_bfloat16* __restrict__ wv, const float* __restrict__ bqk,
    const float* __restrict__ bv, __hip_bfloat16* __restrict__ qk,
    __hip_bfloat16* __restrict__ vT) {
  bool isV = blockIdx.x >= 8;
  int m0 = isV ? (blockIdx.x - 8) * 128 : blockIdx.y * 128;
  int n0 = isV ? blockIdx.y * 128 : blockIdx.x * 128;
  const __hip_bfloat16* A  = isV ? wv : hf;   // [m][512]
  const __hip_bfloat16* Bm = isV ? hf : wqk;  // [n][512]

  __shared__ __align__(16) unsigned char smem[34816];  // dbuf(32K) | epi(34K)
  __hip_bfloat16* As  = (__hip_bfloat16*)smem;
  __hip_bfloat16* Bs  = As + 8192;
  __hip_bfloat16* epi = (__hip_bfloat16*)smem;         // [128][136]

  int tid  = threadIdx.x;
  int wvx  = tid >> 6, lane = tid & 63;
  int wr   = (wvx >> 1) * 64, wc = (wvx & 1) * 64;
  int quad = lane >> 4, l16 = lane & 15;

  int srow = wvx * 32 + (lane >> 2);
  int scol = (lane & 3) * 8;
  const __hip_bfloat16* gA0 = A  + (size_t)(m0 + srow) * 512 + scol;
  const __hip_bfloat16* gA1 = gA0 + (size_t)16 * 512;
  const __hip_bfloat16* gB0 = Bm + (size_t)(n0 + srow) * 512 + scol;
  const __hip_bfloat16* gB1 = gB0 + (size_t)16 * 512;

  auto stage = [&](int kk, int bsel) {
    int lb = bsel * 4096 + wvx * 1024;
    gload_lds16(gA0 + kk, &As[lb]);
    gload_lds16(gA1 + kk, &As[lb + 512]);
    gload_lds16(gB0 + kk, &Bs[lb]);
    gload_lds16(gB1 + kk, &Bs[lb + 512]);
  };

  f32x4 acc[4][4] = {};
  stage(0, 0);
  for (int kt = 0; kt < 16; kt++) {
    __syncthreads();
    if (kt + 1 < 16) stage((kt + 1) << 5, (kt + 1) & 1);
    const __hip_bfloat16* Ab = &As[(kt & 1) * 4096];
    const __hip_bfloat16* Bb = &Bs[(kt & 1) * 4096];
    bf16x8 af[4], bfr[4];
#pragma unroll
    for (int i = 0; i < 4; i++)
      af[i] = *(const bf16x8*)&Ab[(wr + i * 16 + l16) * 32 + quad * 8];
#pragma unroll
    for (int j = 0; j < 4; j++)
      bfr[j] = *(const bf16x8*)&Bb[(wc + j * 16 + l16) * 32 + quad * 8];
#pragma unroll
    for (int i = 0; i < 4; i++)
#pragma unroll
      for (int j = 0; j < 4; j++)
        acc[i][j] = __builtin_amdgcn_mfma_f32_16x16x32_bf16(af[i], bfr[j],
                                                            acc[i][j], 0, 0, 0);
  }

  // ---- epilogue via LDS: C-layout -> row-major coalesced ----
  float bj[4], bm[4][4];
  if (!isV) {
#pragma unroll
    for (int j = 0; j < 4; j++) bj[j] = bqk[n0 + wc + j * 16 + l16];
  } else {
#pragma unroll
    for (int i = 0; i < 4; i++)
#pragma unroll
      for (int r = 0; r < 4; r++)
        bm[i][r] = bv[m0 + wr + i * 16 + quad * 4 + r];
  }
  __syncthreads();  // dbuf fragment reads done before epi overwrite
#pragma unroll
  for (int i = 0; i < 4; i++)
#pragma unroll
    for (int j = 0; j < 4; j++)
#pragma unroll
      for (int r = 0; r < 4; r++) {
        int ml = wr + i * 16 + quad * 4 + r;
        int nl = wc + j * 16 + l16;
        float v = acc[i][j][r] + (isV ? bm[i][r] : bj[j]);
        epi[ml * 136 + nl] = __float2bfloat16(v);
      }
  __syncthreads();
  int mr = tid >> 1, h = tid & 1;
  const __hip_bfloat16* rowp = &epi[mr * 136 + h * 64];
  if (!isV) {
    __hip_bfloat16* o = qk + (size_t)(m0 + mr) * 1024 + n0 + h * 64;
#pragma unroll
    for (int c = 0; c < 8; c++)
      *(uint4*)(o + c * 8) = *(const uint4*)(rowp + c * 8);
  } else {
    int b = (n0 + h * 64) >> 12, t = (n0 + h * 64) & 4095;
    __hip_bfloat16* o = vT + ((size_t)(b * 512 + m0 + mr)) * 4096 + t;
#pragma unroll
    for (int c = 0; c < 8; c++)
      *(uint4*)(o + c * 8) = *(const uint4*)(rowp + c * 8);
  }
}

// ====== fused attention v4: staged V + 2 blocks/CU via LDS phase-overlay ====
// Grid 512 = (2b x 4spl: one group per XCD) x 64 q-tiles(64 rows). 8 waves.
// LDS = 80K exactly -> 2 blocks/CU; the co-resident block's compute hides the
// sibling's barrier drains (the v1->v3 analysis showed barrier latency, not
// bandwidth, is the bound).
// Overlay: union region U[64K] holds {Qs dbuf 16K + Ks dbuf 32K} during the
// QK phase and {Vs ping-pong 2x32K} during the PV phase (strictly disjoint in
// time, separated by barriers). Ps[64][128] XOR-swizzled (16K) lives outside.
// Rs overlays U at the epilogue. All fragment/staging index math is the
// v1-verified code; Ps swizzle is pv_k's production-proven pattern.
__global__ __launch_bounds__(512, 4) void attn_k(
    const __hip_bfloat16* __restrict__ qk, const __hip_bfloat16* __restrict__ vT,
    __hip_bfloat16* __restrict__ part, float* __restrict__ rsum) {
  const float scale = 0.044194173824159216f;
  int bid = blockIdx.x;
  int g = bid & 7;
  int b = g >> 2, spl = g & 3;
  int qtile = bid >> 3;  // 0..63

  const __hip_bfloat16* qkb = qk + (size_t)b * 4194304;
  const __hip_bfloat16* vTb = vT + (size_t)b * 2097152;

  __shared__ __align__(16) unsigned char smem[81920];
  __hip_bfloat16* Qs = (__hip_bfloat16*)smem;             // QK: 2 x [64][64] 16K
  __hip_bfloat16* Ks = (__hip_bfloat16*)(smem + 16384);   // QK: 2 x [128][64] 32K
  __hip_bfloat16* Vs = (__hip_bfloat16*)smem;             // PV: 2 x [512][32] 64K (overlay)
  __hip_bfloat16* Ps = (__hip_bfloat16*)(smem + 65536);   // [64][128] swizzled 16K
  float* Rs = (float*)smem;                               // [4][64] epilogue overlay

  int tid = threadIdx.x, wv = tid >> 6, lane = tid & 63;
  int quad = lane >> 4, l16 = lane & 15;
  int q0 = (wv >> 2) * 32;    // wave q-rows (QK and PV)
  int kvc0 = (wv & 3) * 32;   // wave kv-cols (QK)
  int wd0 = (wv & 3) * 128;   // wave d-cols (PV)

  // QK staging: rows of 64 elems (128B), 8 rows/inst, XOR chunk swizzle
  // LDS[r][c] = G[r][c ^ (r&7)] (16B chunks) -> b128 frag reads spread banks
  int srow8 = lane >> 3;
  int schk = ((lane & 7) ^ srow8) * 8;
  const __hip_bfloat16* gQ =
      qkb + (size_t)(qtile * 64 + wv * 8 + srow8) * 1024 + schk;
  const __hip_bfloat16* gK0 =
      qkb + (size_t)(spl * 1024 + wv * 16 + srow8) * 1024 + 512 + schk;
  const __hip_bfloat16* gK1 = gK0 + (size_t)8 * 1024;

  auto stageQK = [&](int t, int s, int bsel) {
    int koff = t * 131072 + s * 64;  // t*128 rows + s*64 cols
    gload_lds16(gQ + s * 64, &Qs[bsel * 4096 + wv * 512]);
    gload_lds16(gK0 + koff, &Ks[bsel * 8192 + wv * 1024]);
    gload_lds16(gK1 + koff, &Ks[bsel * 8192 + wv * 1024 + 512]);
  };

  // V staging (v1-verified): rows of 32 elems (64B), 16 rows/inst, linear
  const __hip_bfloat16* gV = vTb + (size_t)(wv * 64 + (lane >> 2)) * 4096 +
                             spl * 1024 + (lane & 3) * 8;
  auto stageV = [&](int t, int sub, int vb) {
    const __hip_bfloat16* gvp = gV + t * 128 + sub * 32;
#pragma unroll
    for (int c = 0; c < 4; c++)
      gload_lds16(gvp + (size_t)(c * 16) * 4096, &Vs[vb * 16384 + wv * 2048 + c * 512]);
  };

  f32x4 accS[2][2] = {};
  f32x4 accO[8][2] = {};
  float rsr[8] = {};

  stageQK(0, 0, 0);
  for (int t = 0; t < 8; t++) {
    // ---- QK^T phase: accumulate S over d=512 in 8 dbuf BK=64 stages ----
    for (int s = 0; s < 8; s++) {
      __syncthreads();  // drains stage-s DMA; guards dbuf overwrite
      if (s < 7) stageQK(t, s + 1, (s + 1) & 1);
      const __hip_bfloat16* Qb = &Qs[(s & 1) * 4096];
      const __hip_bfloat16* Kb = &Ks[(s & 1) * 8192];
      bf16x8 aq[2][2], bkf[2][2];
#pragma unroll
      for (int ii = 0; ii < 2; ii++)
#pragma unroll
        for (int kk = 0; kk < 2; kk++) {
          int r = q0 + ii * 16 + l16;
          aq[ii][kk] = *(const bf16x8*)&Qb[r * 64 + ((kk * 4 + quad) ^ (r & 7)) * 8];
        }
#pragma unroll
      for (int jj = 0; jj < 2; jj++)
#pragma unroll
        for (int kk = 0; kk < 2; kk++) {
          int r = kvc0 + jj * 16 + l16;
          bkf[jj][kk] = *(const bf16x8*)&Kb[r * 64 + ((kk * 4 + quad) ^ (r & 7)) * 8];
        }
#pragma unroll
      for (int ii = 0; ii < 2; ii++)
#pragma unroll
        for (int jj = 0; jj < 2; jj++)
#pragma unroll
          for (int kk = 0; kk < 2; kk++)
            accS[ii][jj] = __builtin_amdgcn_mfma_f32_16x16x32_bf16(
                aq[ii][kk], bkf[jj][kk], accS[ii][jj], 0, 0, 0);
    }
    // ---- exp + rowsum, P -> swizzled Ps[64][128] (pv_k's XOR pattern) ----
#pragma unroll
    for (int ii = 0; ii < 2; ii++)
#pragma unroll
      for (int jj = 0; jj < 2; jj++) {
#pragma unroll
        for (int rr = 0; rr < 4; rr++) {
          float p = __expf(accS[ii][jj][rr] * scale);
          rsr[ii * 4 + rr] += p;
          int row = q0 + ii * 16 + quad * 4 + rr;
          int col = kvc0 + jj * 16 + l16;
          Ps[row * 128 + (((col >> 3) ^ (row & 7)) << 3) + (col & 7)] =
              __float2bfloat16(p);
        }
        accS[ii][jj] = (f32x4){0.f, 0.f, 0.f, 0.f};
      }
    __syncthreads();  // (b) all QK reads done + Ps visible -> U is free for V
    stageV(t, 0, 0);
    // ---- PV phase: 4 ping-ponged kv-sub=32 V slabs ----
    for (int sub = 0; sub < 4; sub++) {
      __syncthreads();  // (c) V sub landed; prev sub consumed by all waves
      if (sub < 3) stageV(t, sub + 1, (sub + 1) & 1);
      const __hip_bfloat16* Vb = &Vs[(sub & 1) * 16384];
      bf16x8 pa[2], bvf[8];
#pragma unroll
      for (int ii = 0; ii < 2; ii++) {
        int r = q0 + ii * 16 + l16;
        pa[ii] = *(const bf16x8*)&Ps[r * 128 + (((sub * 4 + quad) ^ (r & 7)) << 3)];
      }
#pragma unroll
      for (int jj = 0; jj < 8; jj++) {
        int r = wd0 + jj * 16 + l16;
        bvf[jj] = *(const bf16x8*)&Vb[r * 32 + quad * 8];
      }
#pragma unroll
      for (int jj = 0; jj < 8; jj++)
#pragma unroll
        for (int ii = 0; ii < 2; ii++)
          accO[jj][ii] = __builtin_amdgcn_mfma_f32_16x16x32_bf16(
              pa[ii], bvf[jj], accO[jj][ii], 0, 0, 0);
    }
    __syncthreads();  // (d) PV reads of Vs done -> U free for next-t QK data
    if (t + 1 < 8) stageQK(t + 1, 0, 0);
  }

  // ---- epilogue: partials (bf16) + per-row expsum ----
  size_t pbase = ((size_t)(spl * 2 + b) * 4096 + qtile * 64) * 512;
#pragma unroll
  for (int ii = 0; ii < 2; ii++)
#pragma unroll
    for (int rr = 0; rr < 4; rr++) {
      int row = q0 + ii * 16 + quad * 4 + rr;
#pragma unroll
      for (int jj = 0; jj < 8; jj++)
        part[pbase + (size_t)row * 512 + wd0 + jj * 16 + l16] =
            __float2bfloat16(accO[jj][ii][rr]);
    }
#pragma unroll
  for (int k = 0; k < 8; k++)
#pragma unroll
    for (int off = 1; off < 16; off <<= 1) rsr[k] += __shfl_xor(rsr[k], off);
  if (l16 == 0) {
#pragma unroll
    for (int ii = 0; ii < 2; ii++)
#pragma unroll
      for (int rr = 0; rr < 4; rr++)
        Rs[(wv & 3) * 64 + q0 + ii * 16 + quad * 4 + rr] = rsr[ii * 4 + rr];
  }
  __syncthreads();
  if (tid < 64)
    rsum[spl * 8192 + b * 4096 + qtile * 64 + tid] =
        Rs[tid] + Rs[64 + tid] + Rs[128 + tid] + Rs[192 + tid];
}

// ---- fold 4 kv-split partials + expsums, normalize -> obuf ----
__global__ __launch_bounds__(256) void reduce2_k(
    const __hip_bfloat16* __restrict__ part, const float* __restrict__ rsum,
    __hip_bfloat16* __restrict__ obuf) {
  size_t i8 = (size_t)blockIdx.x * 256 + threadIdx.x;
  size_t perb = 262144;  // 4096*512/8 vectors per batch
  size_t b = i8 / perb, r = i8 - b * perb;
  int t = (int)(r >> 6);
  float ps = rsum[b * 4096 + t] + rsum[8192 + b * 4096 + t] +
             rsum[16384 + b * 4096 + t] + rsum[24576 + b * 4096 + t];
  float inv = 1.f / ps;
  float acc[8] = {};
#pragma unroll
  for (int sp = 0; sp < 4; sp++) {
    bf16x8 v = ((const bf16x8*)part)[(sp * 2 + b) * perb + r];
#pragma unroll
    for (int l = 0; l < 8; l++) acc[l] += (float)v[l];
  }
  bf16x8 o;
#pragma unroll
  for (int l = 0; l < 8; l++) o[l] = (__bf16)(acc[l] * inv);
  ((bf16x8*)obuf)[b * perb + r] = o;
}

// ====== out-proj, 64x128 tiles (512 blocks = 2/CU vs old 256 = 1/CU) ======
// out[b][c][t] = x[b][c][t] + bf16(sum_o Wo[c][o]*obuf[b][t][o] + bo[c])
__global__ __launch_bounds__(256, 2) void oproj_k(
    const __hip_bfloat16* __restrict__ Wo, const __hip_bfloat16* __restrict__ O,
    float* __restrict__ out, const float* __restrict__ bias,
    const float* __restrict__ resid) {
  int m0 = blockIdx.y * 64, n0 = blockIdx.x * 128, bb = blockIdx.z;
  O += (size_t)bb * 4096 * 512;
  size_t cbase = (size_t)bb * 512 * 4096;

  __shared__ __align__(16) unsigned char smem[24576];  // A 2x4K | B 2x8K; epi
  __hip_bfloat16* As  = (__hip_bfloat16*)smem;          // 2 x [64][32]
  __hip_bfloat16* Bs  = As + 4096;                      // 2 x [128][32]
  __hip_bfloat16* epi = (__hip_bfloat16*)smem;          // [64][136] = 17.4K

  int tid = threadIdx.x, wv = tid >> 6, lane = tid & 63;
  int wr = (wv >> 1) * 32, wc = (wv & 1) * 64;
  int quad = lane >> 4, l16 = lane & 15;

  int lr = lane >> 2, scol = (lane & 3) * 8;
  const __hip_bfloat16* gA  = Wo + (size_t)(m0 + wv * 16 + lr) * 512 + scol;
  const __hip_bfloat16* gB0 = O  + (size_t)(n0 + wv * 32 + lr) * 512 + scol;
  const __hip_bfloat16* gB1 = gB0 + (size_t)16 * 512;

  auto stage = [&](int kk, int bsel) {
    gload_lds16(gA + kk, &As[bsel * 2048 + wv * 512]);
    gload_lds16(gB0 + kk, &Bs[bsel * 4096 + wv * 1024]);
    gload_lds16(gB1 + kk, &Bs[bsel * 4096 + wv * 1024 + 512]);
  };

  f32x4 acc[2][4] = {};
  stage(0, 0);
  for (int kt = 0; kt < 16; kt++) {
    __syncthreads();
    if (kt + 1 < 16) stage((kt + 1) << 5, (kt + 1) & 1);
    const __hip_bfloat16* Ab = &As[(kt & 1) * 2048];
    const __hip_bfloat16* Bb = &Bs[(kt & 1) * 4096];
    bf16x8 af[2], bfr[4];
#pragma unroll
    for (int i = 0; i < 2; i++)
      af[i] = *(const bf16x8*)&Ab[(wr + i * 16 + l16) * 32 + quad * 8];
#pragma unroll
    for (int j = 0; j < 4; j++)
      bfr[j] = *(const bf16x8*)&Bb[(wc + j * 16 + l16) * 32 + quad * 8];
#pragma unroll
    for (int i = 0; i < 2; i++)
#pragma unroll
      for (int j = 0; j < 4; j++)
        acc[i][j] = __builtin_amdgcn_mfma_f32_16x16x32_bf16(af[i], bfr[j],
                                                            acc[i][j], 0, 0, 0);
  }

  float pre[2][4];
#pragma unroll
  for (int i = 0; i < 2; i++)
#pragma unroll
    for (int r = 0; r < 4; r++)
      pre[i][r] = bias[m0 + wr + i * 16 + quad * 4 + r];
  __syncthreads();
#pragma unroll
  for (int i = 0; i < 2; i++)
#pragma unroll
    for (int j = 0; j < 4; j++)
#pragma unroll
      for (int r = 0; r < 4; r++)
        epi[(wr + i * 16 + quad * 4 + r) * 136 + wc + j * 16 + l16] =
            __float2bfloat16(acc[i][j][r] + pre[i][r]);
  __syncthreads();
  int mr = tid >> 2, seg = tid & 3;  // 4 threads/row, 32 elems each
  const __hip_bfloat16* rowp = &epi[mr * 136 + seg * 32];
  size_t obase = cbase + (size_t)(m0 + mr) * 4096 + n0 + seg * 32;
#pragma unroll
  for (int c = 0; c < 4; c++) {
    bf16x8 val = *(const bf16x8*)(rowp + c * 8);
    size_t idx = obase + c * 8;
    float4 r0 = *(const float4*)&resid[idx];
    float4 r1 = *(const float4*)&resid[idx + 4];
    float4 o0, o1;
    o0.x = r0.x + (float)val[0]; o0.y = r0.y + (float)val[1];
    o0.z = r0.z + (float)val[2]; o0.w = r0.w + (float)val[3];
    o1.x = r1.x + (float)val[4]; o1.y = r1.y + (float)val[5];
    o1.z = r1.z + (float)val[6]; o1.w = r1.w + (float)val[7];
    *(float4*)&out[idx] = o0;
    *(float4*)&out[idx + 4] = o1;
  }
}

extern "C" void kernel_launch(void* const* d_in, const int* in_sizes, int n_in,
                              void* d_out, int out_size, void* d_ws,
                              size_t ws_size, hipStream_t stream) {
  const float* xp  = (const float*)d_in[0];
  const float* gwp = (const float*)d_in[1];
  const float* gbp = (const float*)d_in[2];
  const float* wqp = (const float*)d_in[3];
  const float* bqp = (const float*)d_in[4];
  const float* wkp = (const float*)d_in[5];
  const float* bkp = (const float*)d_in[6];
  const float* wvp = (const float*)d_in[7];
  const float* bvp = (const float*)d_in[8];
  const float* wop = (const float*)d_in[9];
  const float* bop = (const float*)d_in[10];
  float* outp = (float*)d_out;

  char* w = (char*)d_ws;
  size_t off = 0;
  auto alloc = [&](size_t bytes) {
    void* p = w + off;
    off += (bytes + 255) & ~(size_t)255;
    return p;
  };
  float* stats         = (float*)alloc(64 * 2 * sizeof(float));
  __hip_bfloat16* hf   = (__hip_bfloat16*)alloc((size_t)2 * 4096 * 512 * 2);
  __hip_bfloat16* wqkb = (__hip_bfloat16*)alloc((size_t)1024 * 512 * 2);
  __hip_bfloat16* wvb  = (__hip_bfloat16*)alloc((size_t)512 * 512 * 2);
  __hip_bfloat16* wob  = (__hip_bfloat16*)alloc((size_t)512 * 512 * 2);
  float* bqk           = (float*)alloc(1024 * sizeof(float));
  float* rsum          = (float*)alloc((size_t)4 * 2 * 4096 * sizeof(float));
  __hip_bfloat16* qk   = (__hip_bfloat16*)alloc((size_t)2 * 4096 * 1024 * 2);
  __hip_bfloat16* vT   = (__hip_bfloat16*)alloc((size_t)2 * 512 * 4096 * 2);
  __hip_bfloat16* obuf = (__hip_bfloat16*)alloc((size_t)2 * 4096 * 512 * 2);
  __hip_bfloat16* part = (__hip_bfloat16*)alloc((size_t)8 * 4096 * 512 * 2);

  // prelude: 4096 cvt blocks + 64 gn_stats blocks + 1 bcat block
  prelude_k<<<4161, 256, 0, stream>>>(wqp, wkp, wvp, wop, wqkb, wvb, wob,
                                      bqp, bkp, bqk, xp, stats);

  gn_apply_k<<<dim3(8, 64, 2), 256, 0, stream>>>(xp, stats, gwp, gbp, hf);

  // fused QKV: qk[8192][1024] and vT[2][512][4096]
  qkv_k<<<dim3(12, 64, 1), 256, 0, stream>>>(hf, wqkb, wvb, bqk, bvp, qk, vT);

  // fused attention v4: 512 blocks (2/CU via 80K LDS overlay), kv-split 4
  attn_k<<<512, 512, 0, stream>>>(qk, vT, part, rsum);

  // fold 4 partials + expsums, normalize -> obuf
  reduce2_k<<<2048, 256, 0, stream>>>(part, rsum, obuf);

  // out[b][c][t] = x + Wo*O + bo  (64x128 tiles, 512 blocks)
  oproj_k<<<dim3(32, 8, 2), 256, 0, stream>>>(wob, obuf, outp, bop, xp);
}

// Round 5
// 315.184 us; speedup vs baseline: 1.1988x; 1.0569x over previous
//
#include <hip/hip_runtime.h>
#include <hip/hip_bf16.h>

// Problem constants: B=2, C=512, H=W=64 -> N=4096, G=32 (16 ch/group), EPS=1e-6.

typedef float f32x4 __attribute__((ext_vector_type(4)));
typedef __bf16 bf16x8 __attribute__((ext_vector_type(8)));

typedef const __attribute__((address_space(1))) unsigned char* gas_p;
typedef __attribute__((address_space(3))) unsigned char* las_p;

__device__ __forceinline__ void gload_lds16(const void* g, void* l) {
  // async DMA: each lane contributes 16B; LDS dst = wave-uniform base + lane*16
  __builtin_amdgcn_global_load_lds((gas_p)g, (las_p)l, 16, 0, 0);
}

// ====== prelude: weight cvt (4x1024 blocks) | gn_stats (64) | bcat (1) ======
__global__ __launch_bounds__(256) void prelude_k(
    const float* __restrict__ wq, const float* __restrict__ wk,
    const float* __restrict__ wv, const float* __restrict__ wo,
    __hip_bfloat16* __restrict__ wqkb, __hip_bfloat16* __restrict__ wvb,
    __hip_bfloat16* __restrict__ wob, const float* __restrict__ bq,
    const float* __restrict__ bk, float* __restrict__ bqk,
    const float* __restrict__ x, float* __restrict__ stats) {
  int bid = blockIdx.x;
  if (bid < 4096) {
    const float* src;
    __hip_bfloat16* dst;
    if (bid < 1024)      { src = wq; dst = wqkb; }
    else if (bid < 2048) { src = wk; dst = wqkb + 262144; }
    else if (bid < 3072) { src = wv; dst = wvb; }
    else                 { src = wo; dst = wob; }
    int i = (bid & 1023) * 256 + threadIdx.x;  // 1024*256 = 262144 = 512*512
    dst[i] = __float2bfloat16(src[i]);
    return;
  }
  if (bid < 4160) {  // gn_stats: one block per (b,g)
    int bg = bid - 4096;
    const float4* p = (const float4*)(x + (size_t)bg * 65536);
    float s = 0.f, s2 = 0.f;
    for (int i = threadIdx.x; i < 16384; i += 256) {
      float4 v = p[i];
      s  += v.x + v.y + v.z + v.w;
      s2 += v.x * v.x + v.y * v.y + v.z * v.z + v.w * v.w;
    }
#pragma unroll
    for (int off = 32; off > 0; off >>= 1) {
      s  += __shfl_xor(s, off);
      s2 += __shfl_xor(s2, off);
    }
    __shared__ float rs[4], rs2[4];
    int wid = threadIdx.x >> 6, lane = threadIdx.x & 63;
    if (lane == 0) { rs[wid] = s; rs2[wid] = s2; }
    __syncthreads();
    if (threadIdx.x == 0) {
      float S  = rs[0] + rs[1] + rs[2] + rs[3];
      float S2 = rs2[0] + rs2[1] + rs2[2] + rs2[3];
      float mean = S * (1.f / 65536.f);
      float var  = S2 * (1.f / 65536.f) - mean * mean;
      stats[bg * 2]     = mean;
      stats[bg * 2 + 1] = rsqrtf(var + 1e-6f);
    }
    return;
  }
  // bcat
  for (int j = threadIdx.x; j < 1024; j += 256)
    bqk[j] = (j < 512) ? bq[j] : bk[j - 512];
}

// ------- GroupNorm apply + transpose, vectorized: x fp32 -> hf bf16 [b][n][c]
__global__ __launch_bounds__(256) void gn_apply_k(const float* __restrict__ x,
                                                  const float* __restrict__ stats,
                                                  const float* __restrict__ gw,
                                                  const float* __restrict__ gb,
                                                  __hip_bfloat16* __restrict__ hf) {
  int c0 = blockIdx.x * 64, n0 = blockIdx.y * 64, b = blockIdx.z;
  __shared__ float tile[64][65];
  int tid = threadIdx.x;
  int cl = tid >> 2, q = tid & 3;
  int c = c0 + cl;
  float mean = stats[(b * 32 + (c >> 4)) * 2];
  float rstd = stats[(b * 32 + (c >> 4)) * 2 + 1];
  float sc = rstd * gw[c];
  float sh = gb[c] - mean * sc;
  const float* xr = x + ((size_t)(b * 512 + c0 + cl)) * 4096 + n0 + q * 16;
#pragma unroll
  for (int j = 0; j < 4; j++) {
    float4 v = *(const float4*)(xr + 4 * j);
    int n = q * 16 + 4 * j;
    tile[cl][n]     = v.x * sc + sh;
    tile[cl][n + 1] = v.y * sc + sh;
    tile[cl][n + 2] = v.z * sc + sh;
    tile[cl][n + 3] = v.w * sc + sh;
  }
  __syncthreads();
  int nl = tid >> 2, ch = q * 16;
  bf16x8 o0, o1;
#pragma unroll
  for (int l = 0; l < 8; l++) {
    o0[l] = (__bf16)tile[ch + l][nl];
    o1[l] = (__bf16)tile[ch + 8 + l][nl];
  }
  __hip_bfloat16* op = hf + ((size_t)(b * 4096 + n0 + nl)) * 512 + c0 + ch;
  *(uint4*)op = *(uint4*)&o0;
  *(uint4*)(op + 8) = *(uint4*)&o1;
}

// ============ fused QKV (double-buffered DMA + LDS epilogue) ============
// bx<8 : QK GEMM  qk[t][o] (o<1024) = sum_c hf[t][c]*Wqk[o][c] + bqk[o]
// bx>=8: V GEMM   vT[b][o][t]       = sum_c Wv[o][c]*hf[t][c] + bv[o]
__global__ __launch_bounds__(256, 4) void qkv_k(
    const __hip_bfloat16* __restrict__ hf, const __hip_bfloat16* __restrict__ wqk,
    const __hip_bfloat16* __restrict__ wv, const float* __restrict__ bqk,
    const float* __restrict__ bv, __hip_bfloat16* __restrict__ qk,
    __hip_bfloat16* __restrict__ vT) {
  bool isV = blockIdx.x >= 8;
  int m0 = isV ? (blockIdx.x - 8) * 128 : blockIdx.y * 128;
  int n0 = isV ? blockIdx.y * 128 : blockIdx.x * 128;
  const __hip_bfloat16* A  = isV ? wv : hf;   // [m][512]
  const __hip_bfloat16* Bm = isV ? hf : wqk;  // [n][512]

  __shared__ __align__(16) unsigned char smem[34816];  // dbuf(32K) | epi(34K)
  __hip_bfloat16* As  = (__hip_bfloat16*)smem;
  __hip_bfloat16* Bs  = As + 8192;
  __hip_bfloat16* epi = (__hip_bfloat16*)smem;         // [128][136]

  int tid  = threadIdx.x;
  int wvx  = tid >> 6, lane = tid & 63;
  int wr   = (wvx >> 1) * 64, wc = (wvx & 1) * 64;
  int quad = lane >> 4, l16 = lane & 15;

  int srow = wvx * 32 + (lane >> 2);
  int scol = (lane & 3) * 8;
  const __hip_bfloat16* gA0 = A  + (size_t)(m0 + srow) * 512 + scol;
  const __hip_bfloat16* gA1 = gA0 + (size_t)16 * 512;
  const __hip_bfloat16* gB0 = Bm + (size_t)(n0 + srow) * 512 + scol;
  const __hip_bfloat16* gB1 = gB0 + (size_t)16 * 512;

  auto stage = [&](int kk, int bsel) {
    int lb = bsel * 4096 + wvx * 1024;
    gload_lds16(gA0 + kk, &As[lb]);
    gload_lds16(gA1 + kk, &As[lb + 512]);
    gload_lds16(gB0 + kk, &Bs[lb]);
    gload_lds16(gB1 + kk, &Bs[lb + 512]);
  };

  f32x4 acc[4][4] = {};
  stage(0, 0);
  for (int kt = 0; kt < 16; kt++) {
    __syncthreads();
    if (kt + 1 < 16) stage((kt + 1) << 5, (kt + 1) & 1);
    const __hip_bfloat16* Ab = &As[(kt & 1) * 4096];
    const __hip_bfloat16* Bb = &Bs[(kt & 1) * 4096];
    bf16x8 af[4], bfr[4];
#pragma unroll
    for (int i = 0; i < 4; i++)
      af[i] = *(const bf16x8*)&Ab[(wr + i * 16 + l16) * 32 + quad * 8];
#pragma unroll
    for (int j = 0; j < 4; j++)
      bfr[j] = *(const bf16x8*)&Bb[(wc + j * 16 + l16) * 32 + quad * 8];
#pragma unroll
    for (int i = 0; i < 4; i++)
#pragma unroll
      for (int j = 0; j < 4; j++)
        acc[i][j] = __builtin_amdgcn_mfma_f32_16x16x32_bf16(af[i], bfr[j],
                                                            acc[i][j], 0, 0, 0);
  }

  // ---- epilogue via LDS: C-layout -> row-major coalesced ----
  float bj[4], bm[4][4];
  if (!isV) {
#pragma unroll
    for (int j = 0; j < 4; j++) bj[j] = bqk[n0 + wc + j * 16 + l16];
  } else {
#pragma unroll
    for (int i = 0; i < 4; i++)
#pragma unroll
      for (int r = 0; r < 4; r++)
        bm[i][r] = bv[m0 + wr + i * 16 + quad * 4 + r];
  }
  __syncthreads();  // dbuf fragment reads done before epi overwrite
#pragma unroll
  for (int i = 0; i < 4; i++)
#pragma unroll
    for (int j = 0; j < 4; j++)
#pragma unroll
      for (int r = 0; r < 4; r++) {
        int ml = wr + i * 16 + quad * 4 + r;
        int nl = wc + j * 16 + l16;
        float v = acc[i][j][r] + (isV ? bm[i][r] : bj[j]);
        epi[ml * 136 + nl] = __float2bfloat16(v);
      }
  __syncthreads();
  int mr = tid >> 1, h = tid & 1;
  const __hip_bfloat16* rowp = &epi[mr * 136 + h * 64];
  if (!isV) {
    __hip_bfloat16* o = qk + (size_t)(m0 + mr) * 1024 + n0 + h * 64;
#pragma unroll
    for (int c = 0; c < 8; c++)
      *(uint4*)(o + c * 8) = *(const uint4*)(rowp + c * 8);
  } else {
    int b = (n0 + h * 64) >> 12, t = (n0 + h * 64) & 4095;
    __hip_bfloat16* o = vT + ((size_t)(b * 512 + m0 + mr)) * 4096 + t;
#pragma unroll
    for (int c = 0; c < 8; c++)
      *(uint4*)(o + c * 8) = *(const uint4*)(rowp + c * 8);
  }
}

// ====== fused attention v5: persistent-Q QBLK=32, 2 blocks/CU, staged V =====
// Grid 1024 = (2b x 4spl: one group per XCD via bid&7) x 128 q-tiles(32 rows).
// 8 waves, LDS 74.2K -> 2 blocks/CU. Q[32][512] staged ONCE (swizzled,
// persistent) -- kills v4's 256MB of Q re-fetch HBM thrash. K dbuf (32K) and
// single-buffered V slab [512][32] (32K) share a time-disjoint union region.
// V sub-0 DMA is issued before the exp/Ps phase so VALU work hides it.
__global__ __launch_bounds__(512, 4) void attn_k(
    const __hip_bfloat16* __restrict__ qk, const __hip_bfloat16* __restrict__ vT,
    __hip_bfloat16* __restrict__ part, float* __restrict__ rsum) {
  const float scale = 0.044194173824159216f;
  int bid = blockIdx.x;
  int g = bid & 7;
  int b = g >> 2, spl = g & 3;
  int qtile = bid >> 3;  // 0..127

  const __hip_bfloat16* qkb = qk + (size_t)b * 4194304;
  const __hip_bfloat16* vTb = vT + (size_t)b * 2097152;

  __shared__ __align__(16) unsigned char smem[74240];
  __hip_bfloat16* Qs = (__hip_bfloat16*)smem;             // [32][512] swz, 32K
  __hip_bfloat16* Us = (__hip_bfloat16*)(smem + 32768);   // union 32K: K dbuf | V slab
  __hip_bfloat16* Ps = (__hip_bfloat16*)(smem + 65536);   // [32][128] swz, 8K
  float* Rs = (float*)(smem + 73728);                     // [4][32]
  __hip_bfloat16* Ks = Us;   // 2 x [128][64]
  __hip_bfloat16* Vs = Us;   // [512][32]

  int tid = threadIdx.x, wv = tid >> 6, lane = tid & 63;
  int quad = lane >> 4, l16 = lane & 15;
  int q0 = (wv >> 2) * 16;    // wave q-rows (16)
  int kvc0 = (wv & 3) * 32;   // wave kv-cols (QK)
  int wd0 = (wv & 3) * 128;   // wave d-cols (PV)

  // ---- persistent Q: LDS[r][chunk c] = G[r][c ^ (r&7)] (16B chunks) ----
#pragma unroll
  for (int i = 0; i < 4; i++) {
    int r = wv * 4 + i;
    gload_lds16(qkb + (size_t)(qtile * 32 + r) * 1024 + (lane ^ (r & 7)) * 8,
                &Qs[r * 512]);
  }

  // K staging (v1-verified geometry): rows of 64 elems, 8 rows/inst, XOR swz
  int srow8 = lane >> 3;
  int schk = ((lane & 7) ^ srow8) * 8;
  const __hip_bfloat16* gK0 =
      qkb + (size_t)(spl * 1024 + wv * 16 + srow8) * 1024 + 512 + schk;
  const __hip_bfloat16* gK1 = gK0 + (size_t)8 * 1024;
  auto stageK = [&](int t, int s, int bsel) {
    int koff = t * 131072 + s * 64;  // t*128 rows + s*64 cols
    gload_lds16(gK0 + koff, &Ks[bsel * 8192 + wv * 1024]);
    gload_lds16(gK1 + koff, &Ks[bsel * 8192 + wv * 1024 + 512]);
  };

  // V staging (v1-verified): [512 d][32 kv] slab, 16 rows/inst, linear
  const __hip_bfloat16* gV = vTb + (size_t)(wv * 64 + (lane >> 2)) * 4096 +
                             spl * 1024 + (lane & 3) * 8;
  auto stageV = [&](int t, int sub) {
    const __hip_bfloat16* gvp = gV + t * 128 + sub * 32;
#pragma unroll
    for (int c = 0; c < 4; c++)
      gload_lds16(gvp + (size_t)(c * 16) * 4096, &Vs[wv * 2048 + c * 512]);
  };

  f32x4 accS[2] = {};
  f32x4 accO[8] = {};
  float rsr[4] = {};

  stageK(0, 0, 0);
  for (int t = 0; t < 8; t++) {
    // ---- QK^T: S[32][128] over d=512 in 8 dbuf BK=64 stages ----
    for (int s = 0; s < 8; s++) {
      __syncthreads();  // K stage-s landed (t=0,s=0 also drains Q staging)
      if (s < 7) stageK(t, s + 1, (s + 1) & 1);
      const __hip_bfloat16* Kb = &Ks[(s & 1) * 8192];
      int rq = q0 + l16;
#pragma unroll
      for (int kk = 0; kk < 2; kk++) {
        bf16x8 aq = *(const bf16x8*)
            &Qs[rq * 512 + ((s * 8 + kk * 4 + quad) ^ (rq & 7)) * 8];
#pragma unroll
        for (int jj = 0; jj < 2; jj++) {
          int r = kvc0 + jj * 16 + l16;
          bf16x8 bk = *(const bf16x8*)&Kb[r * 64 + ((kk * 4 + quad) ^ (r & 7)) * 8];
          accS[jj] = __builtin_amdgcn_mfma_f32_16x16x32_bf16(aq, bk, accS[jj],
                                                             0, 0, 0);
        }
      }
    }
    __syncthreads();  // (A) all K reads done -> U free for V
    stageV(t, 0);     // V sub-0 DMA overlaps the exp/Ps phase below
    // ---- exp + rowsum, P -> swizzled Ps[32][128] ----
#pragma unroll
    for (int jj = 0; jj < 2; jj++) {
#pragma unroll
      for (int rr = 0; rr < 4; rr++) {
        float p = __expf(accS[jj][rr] * scale);
        rsr[rr] += p;
        int row = q0 + quad * 4 + rr;
        int col = kvc0 + jj * 16 + l16;
        Ps[row * 128 + (((col >> 3) ^ (row & 7)) << 3) + (col & 7)] =
            __float2bfloat16(p);
      }
      accS[jj] = (f32x4){0.f, 0.f, 0.f, 0.f};
    }
    // ---- PV: 4 single-buffered kv-sub=32 V slabs ----
    for (int sub = 0; sub < 4; sub++) {
      __syncthreads();  // (B) V landed (+ Ps visible at sub 0)
      int rq = q0 + l16;
      bf16x8 pa = *(const bf16x8*)
          &Ps[rq * 128 + (((sub * 4 + quad) ^ (rq & 7)) << 3)];
#pragma unroll
      for (int jj = 0; jj < 8; jj++) {
        int r = wd0 + jj * 16 + l16;
        bf16x8 bvf = *(const bf16x8*)&Vs[r * 32 + quad * 8];
        accO[jj] = __builtin_amdgcn_mfma_f32_16x16x32_bf16(pa, bvf, accO[jj],
                                                           0, 0, 0);
      }
      __syncthreads();  // (C) V consumed -> safe to overwrite U
      if (sub < 3) stageV(t, sub + 1);
      else if (t + 1 < 8) stageK(t + 1, 0, 0);
    }
  }

  // ---- epilogue: partials (bf16) + per-row expsum ----
  size_t pbase = ((size_t)(spl * 2 + b) * 4096 + qtile * 32) * 512;
#pragma unroll
  for (int rr = 0; rr < 4; rr++) {
    int row = q0 + quad * 4 + rr;
#pragma unroll
    for (int jj = 0; jj < 8; jj++)
      part[pbase + (size_t)row * 512 + wd0 + jj * 16 + l16] =
          __float2bfloat16(accO[jj][rr]);
  }
#pragma unroll
  for (int k = 0; k < 4; k++)
#pragma unroll
    for (int off = 1; off < 16; off <<= 1) rsr[k] += __shfl_xor(rsr[k], off);
  if (l16 == 0) {
#pragma unroll
    for (int rr = 0; rr < 4; rr++)
      Rs[(wv & 3) * 32 + q0 + quad * 4 + rr] = rsr[rr];
  }
  __syncthreads();
  if (tid < 32)
    rsum[spl * 8192 + b * 4096 + qtile * 32 + tid] =
        Rs[tid] + Rs[32 + tid] + Rs[64 + tid] + Rs[96 + tid];
}

// ---- fold 4 kv-split partials + expsums, normalize -> obuf ----
__global__ __launch_bounds__(256) void reduce2_k(
    const __hip_bfloat16* __restrict__ part, const float* __restrict__ rsum,
    __hip_bfloat16* __restrict__ obuf) {
  size_t i8 = (size_t)blockIdx.x * 256 + threadIdx.x;
  size_t perb = 262144;  // 4096*512/8 vectors per batch
  size_t b = i8 / perb, r = i8 - b * perb;
  int t = (int)(r >> 6);
  float ps = rsum[b * 4096 + t] + rsum[8192 + b * 4096 + t] +
             rsum[16384 + b * 4096 + t] + rsum[24576 + b * 4096 + t];
  float inv = 1.f / ps;
  float acc[8] = {};
#pragma unroll
  for (int sp = 0; sp < 4; sp++) {
    bf16x8 v = ((const bf16x8*)part)[(sp * 2 + b) * perb + r];
#pragma unroll
    for (int l = 0; l < 8; l++) acc[l] += (float)v[l];
  }
  bf16x8 o;
#pragma unroll
  for (int l = 0; l < 8; l++) o[l] = (__bf16)(acc[l] * inv);
  ((bf16x8*)obuf)[b * perb + r] = o;
}

// ====== out-proj, 64x128 tiles (512 blocks = 2/CU vs old 256 = 1/CU) ======
// out[b][c][t] = x[b][c][t] + bf16(sum_o Wo[c][o]*obuf[b][t][o] + bo[c])
__global__ __launch_bounds__(256, 2) void oproj_k(
    const __hip_bfloat16* __restrict__ Wo, const __hip_bfloat16* __restrict__ O,
    float* __restrict__ out, const float* __restrict__ bias,
    const float* __restrict__ resid) {
  int m0 = blockIdx.y * 64, n0 = blockIdx.x * 128, bb = blockIdx.z;
  O += (size_t)bb * 4096 * 512;
  size_t cbase = (size_t)bb * 512 * 4096;

  __shared__ __align__(16) unsigned char smem[24576];  // A 2x4K | B 2x8K; epi
  __hip_bfloat16* As  = (__hip_bfloat16*)smem;          // 2 x [64][32]
  __hip_bfloat16* Bs  = As + 4096;                      // 2 x [128][32]
  __hip_bfloat16* epi = (__hip_bfloat16*)smem;          // [64][136] = 17.4K

  int tid = threadIdx.x, wv = tid >> 6, lane = tid & 63;
  int wr = (wv >> 1) * 32, wc = (wv & 1) * 64;
  int quad = lane >> 4, l16 = lane & 15;

  int lr = lane >> 2, scol = (lane & 3) * 8;
  const __hip_bfloat16* gA  = Wo + (size_t)(m0 + wv * 16 + lr) * 512 + scol;
  const __hip_bfloat16* gB0 = O  + (size_t)(n0 + wv * 32 + lr) * 512 + scol;
  const __hip_bfloat16* gB1 = gB0 + (size_t)16 * 512;

  auto stage = [&](int kk, int bsel) {
    gload_lds16(gA + kk, &As[bsel * 2048 + wv * 512]);
    gload_lds16(gB0 + kk, &Bs[bsel * 4096 + wv * 1024]);
    gload_lds16(gB1 + kk, &Bs[bsel * 4096 + wv * 1024 + 512]);
  };

  f32x4 acc[2][4] = {};
  stage(0, 0);
  for (int kt = 0; kt < 16; kt++) {
    __syncthreads();
    if (kt + 1 < 16) stage((kt + 1) << 5, (kt + 1) & 1);
    const __hip_bfloat16* Ab = &As[(kt & 1) * 2048];
    const __hip_bfloat16* Bb = &Bs[(kt & 1) * 4096];
    bf16x8 af[2], bfr[4];
#pragma unroll
    for (int i = 0; i < 2; i++)
      af[i] = *(const bf16x8*)&Ab[(wr + i * 16 + l16) * 32 + quad * 8];
#pragma unroll
    for (int j = 0; j < 4; j++)
      bfr[j] = *(const bf16x8*)&Bb[(wc + j * 16 + l16) * 32 + quad * 8];
#pragma unroll
    for (int i = 0; i < 2; i++)
#pragma unroll
      for (int j = 0; j < 4; j++)
        acc[i][j] = __builtin_amdgcn_mfma_f32_16x16x32_bf16(af[i], bfr[j],
                                                            acc[i][j], 0, 0, 0);
  }

  float pre[2][4];
#pragma unroll
  for (int i = 0; i < 2; i++)
#pragma unroll
    for (int r = 0; r < 4; r++)
      pre[i][r] = bias[m0 + wr + i * 16 + quad * 4 + r];
  __syncthreads();
#pragma unroll
  for (int i = 0; i < 2; i++)
#pragma unroll
    for (int j = 0; j < 4; j++)
#pragma unroll
      for (int r = 0; r < 4; r++)
        epi[(wr + i * 16 + quad * 4 + r) * 136 + wc + j * 16 + l16] =
            __float2bfloat16(acc[i][j][r] + pre[i][r]);
  __syncthreads();
  int mr = tid >> 2, seg = tid & 3;  // 4 threads/row, 32 elems each
  const __hip_bfloat16* rowp = &epi[mr * 136 + seg * 32];
  size_t obase = cbase + (size_t)(m0 + mr) * 4096 + n0 + seg * 32;
#pragma unroll
  for (int c = 0; c < 4; c++) {
    bf16x8 val = *(const bf16x8*)(rowp + c * 8);
    size_t idx = obase + c * 8;
    float4 r0 = *(const float4*)&resid[idx];
    float4 r1 = *(const float4*)&resid[idx + 4];
    float4 o0, o1;
    o0.x = r0.x + (float)val[0]; o0.y = r0.y + (float)val[1];
    o0.z = r0.z + (float)val[2]; o0.w = r0.w + (float)val[3];
    o1.x = r1.x + (float)val[4]; o1.y = r1.y + (float)val[5];
    o1.z = r1.z + (float)val[6]; o1.w = r1.w + (float)val[7];
    *(float4*)&out[idx] = o0;
    *(float4*)&out[idx + 4] = o1;
  }
}

extern "C" void kernel_launch(void* const* d_in, const int* in_sizes, int n_in,
                              void* d_out, int out_size, void* d_ws,
                              size_t ws_size, hipStream_t stream) {
  const float* xp  = (const float*)d_in[0];
  const float* gwp = (const float*)d_in[1];
  const float* gbp = (const float*)d_in[2];
  const float* wqp = (const float*)d_in[3];
  const float* bqp = (const float*)d_in[4];
  const float* wkp = (const float*)d_in[5];
  const float* bkp = (const float*)d_in[6];
  const float* wvp = (const float*)d_in[7];
  const float* bvp = (const float*)d_in[8];
  const float* wop = (const float*)d_in[9];
  const float* bop = (const float*)d_in[10];
  float* outp = (float*)d_out;

  char* w = (char*)d_ws;
  size_t off = 0;
  auto alloc = [&](size_t bytes) {
    void* p = w + off;
    off += (bytes + 255) & ~(size_t)255;
    return p;
  };
  float* stats         = (float*)alloc(64 * 2 * sizeof(float));
  __hip_bfloat16* hf   = (__hip_bfloat16*)alloc((size_t)2 * 4096 * 512 * 2);
  __hip_bfloat16* wqkb = (__hip_bfloat16*)alloc((size_t)1024 * 512 * 2);
  __hip_bfloat16* wvb  = (__hip_bfloat16*)alloc((size_t)512 * 512 * 2);
  __hip_bfloat16* wob  = (__hip_bfloat16*)alloc((size_t)512 * 512 * 2);
  float* bqk           = (float*)alloc(1024 * sizeof(float));
  float* rsum          = (float*)alloc((size_t)4 * 2 * 4096 * sizeof(float));
  __hip_bfloat16* qk   = (__hip_bfloat16*)alloc((size_t)2 * 4096 * 1024 * 2);
  __hip_bfloat16* vT   = (__hip_bfloat16*)alloc((size_t)2 * 512 * 4096 * 2);
  __hip_bfloat16* obuf = (__hip_bfloat16*)alloc((size_t)2 * 4096 * 512 * 2);
  __hip_bfloat16* part = (__hip_bfloat16*)alloc((size_t)8 * 4096 * 512 * 2);

  // prelude: 4096 cvt blocks + 64 gn_stats blocks + 1 bcat block
  prelude_k<<<4161, 256, 0, stream>>>(wqp, wkp, wvp, wop, wqkb, wvb, wob,
                                      bqp, bkp, bqk, xp, stats);

  gn_apply_k<<<dim3(8, 64, 2), 256, 0, stream>>>(xp, stats, gwp, gbp, hf);

  // fused QKV: qk[8192][1024] and vT[2][512][4096]
  qkv_k<<<dim3(12, 64, 1), 256, 0, stream>>>(hf, wqkb, wvb, bqk, bvp, qk, vT);

  // fused attention v5: 1024 blocks (2/CU, 74K LDS), persistent Q, kv-split 4
  attn_k<<<1024, 512, 0, stream>>>(qk, vT, part, rsum);

  // fold 4 partials + expsums, normalize -> obuf
  reduce2_k<<<2048, 256, 0, stream>>>(part, rsum, obuf);

  // out[b][c][t] = x + Wo*O + bo  (64x128 tiles, 512 blocks)
  oproj_k<<<dim3(32, 8, 2), 256, 0, stream>>>(wob, obuf, outp, bop, xp);
}

// Round 6
// 284.212 us; speedup vs baseline: 1.3295x; 1.1090x over previous
//
#include <hip/hip_runtime.h>
#include <hip/hip_bf16.h>

// Problem constants: B=2, C=512, H=W=64 -> N=4096, G=32 (16 ch/group), EPS=1e-6.

typedef float f32x4 __attribute__((ext_vector_type(4)));
typedef __bf16 bf16x8 __attribute__((ext_vector_type(8)));

typedef const __attribute__((address_space(1))) unsigned char* gas_p;
typedef __attribute__((address_space(3))) unsigned char* las_p;

__device__ __forceinline__ void gload_lds16(const void* g, void* l) {
  // async DMA: each lane contributes 16B; LDS dst = wave-uniform base + lane*16
  __builtin_amdgcn_global_load_lds((gas_p)g, (las_p)l, 16, 0, 0);
}

// ====== prelude: weight cvt (4x1024 blocks) | gn_stats (64) | bcat (1) ======
__global__ __launch_bounds__(256) void prelude_k(
    const float* __restrict__ wq, const float* __restrict__ wk,
    const float* __restrict__ wv, const float* __restrict__ wo,
    __hip_bfloat16* __restrict__ wqkb, __hip_bfloat16* __restrict__ wvb,
    __hip_bfloat16* __restrict__ wob, const float* __restrict__ bq,
    const float* __restrict__ bk, float* __restrict__ bqk,
    const float* __restrict__ x, float* __restrict__ stats) {
  int bid = blockIdx.x;
  if (bid < 4096) {
    const float* src;
    __hip_bfloat16* dst;
    if (bid < 1024)      { src = wq; dst = wqkb; }
    else if (bid < 2048) { src = wk; dst = wqkb + 262144; }
    else if (bid < 3072) { src = wv; dst = wvb; }
    else                 { src = wo; dst = wob; }
    int i = (bid & 1023) * 256 + threadIdx.x;  // 1024*256 = 262144 = 512*512
    dst[i] = __float2bfloat16(src[i]);
    return;
  }
  if (bid < 4160) {  // gn_stats: one block per (b,g)
    int bg = bid - 4096;
    const float4* p = (const float4*)(x + (size_t)bg * 65536);
    float s = 0.f, s2 = 0.f;
    for (int i = threadIdx.x; i < 16384; i += 256) {
      float4 v = p[i];
      s  += v.x + v.y + v.z + v.w;
      s2 += v.x * v.x + v.y * v.y + v.z * v.z + v.w * v.w;
    }
#pragma unroll
    for (int off = 32; off > 0; off >>= 1) {
      s  += __shfl_xor(s, off);
      s2 += __shfl_xor(s2, off);
    }
    __shared__ float rs[4], rs2[4];
    int wid = threadIdx.x >> 6, lane = threadIdx.x & 63;
    if (lane == 0) { rs[wid] = s; rs2[wid] = s2; }
    __syncthreads();
    if (threadIdx.x == 0) {
      float S  = rs[0] + rs[1] + rs[2] + rs[3];
      float S2 = rs2[0] + rs2[1] + rs2[2] + rs2[3];
      float mean = S * (1.f / 65536.f);
      float var  = S2 * (1.f / 65536.f) - mean * mean;
      stats[bg * 2]     = mean;
      stats[bg * 2 + 1] = rsqrtf(var + 1e-6f);
    }
    return;
  }
  // bcat
  for (int j = threadIdx.x; j < 1024; j += 256)
    bqk[j] = (j < 512) ? bq[j] : bk[j - 512];
}

// ------- GroupNorm apply + transpose, vectorized: x fp32 -> hf bf16 [b][n][c]
__global__ __launch_bounds__(256) void gn_apply_k(const float* __restrict__ x,
                                                  const float* __restrict__ stats,
                                                  const float* __restrict__ gw,
                                                  const float* __restrict__ gb,
                                                  __hip_bfloat16* __restrict__ hf) {
  int c0 = blockIdx.x * 64, n0 = blockIdx.y * 64, b = blockIdx.z;
  __shared__ float tile[64][65];
  int tid = threadIdx.x;
  int cl = tid >> 2, q = tid & 3;
  int c = c0 + cl;
  float mean = stats[(b * 32 + (c >> 4)) * 2];
  float rstd = stats[(b * 32 + (c >> 4)) * 2 + 1];
  float sc = rstd * gw[c];
  float sh = gb[c] - mean * sc;
  const float* xr = x + ((size_t)(b * 512 + c0 + cl)) * 4096 + n0 + q * 16;
#pragma unroll
  for (int j = 0; j < 4; j++) {
    float4 v = *(const float4*)(xr + 4 * j);
    int n = q * 16 + 4 * j;
    tile[cl][n]     = v.x * sc + sh;
    tile[cl][n + 1] = v.y * sc + sh;
    tile[cl][n + 2] = v.z * sc + sh;
    tile[cl][n + 3] = v.w * sc + sh;
  }
  __syncthreads();
  int nl = tid >> 2, ch = q * 16;
  bf16x8 o0, o1;
#pragma unroll
  for (int l = 0; l < 8; l++) {
    o0[l] = (__bf16)tile[ch + l][nl];
    o1[l] = (__bf16)tile[ch + 8 + l][nl];
  }
  __hip_bfloat16* op = hf + ((size_t)(b * 4096 + n0 + nl)) * 512 + c0 + ch;
  *(uint4*)op = *(uint4*)&o0;
  *(uint4*)(op + 8) = *(uint4*)&o1;
}

// ============ fused QKV (double-buffered DMA + LDS epilogue) ============
// bx<8 : QK GEMM  qk[t][o] (o<1024) = sum_c hf[t][c]*Wqk[o][c] + bqk[o]
// bx>=8: V GEMM   vT[b][o][t]       = sum_c Wv[o][c]*hf[t][c] + bv[o]
__global__ __launch_bounds__(256, 4) void qkv_k(
    const __hip_bfloat16* __restrict__ hf, const __hip_bfloat16* __restrict__ wqk,
    const __hip_bfloat16* __restrict__ wv, const float* __restrict__ bqk,
    const float* __restrict__ bv, __hip_bfloat16* __restrict__ qk,
    __hip_bfloat16* __restrict__ vT) {
  bool isV = blockIdx.x >= 8;
  int m0 = isV ? (blockIdx.x - 8) * 128 : blockIdx.y * 128;
  int n0 = isV ? blockIdx.y * 128 : blockIdx.x * 128;
  const __hip_bfloat16* A  = isV ? wv : hf;   // [m][512]
  const __hip_bfloat16* Bm = isV ? hf : wqk;  // [n][512]

  __shared__ __align__(16) unsigned char smem[34816];  // dbuf(32K) | epi(34K)
  __hip_bfloat16* As  = (__hip_bfloat16*)smem;
  __hip_bfloat16* Bs  = As + 8192;
  __hip_bfloat16* epi = (__hip_bfloat16*)smem;         // [128][136]

  int tid  = threadIdx.x;
  int wvx  = tid >> 6, lane = tid & 63;
  int wr   = (wvx >> 1) * 64, wc = (wvx & 1) * 64;
  int quad = lane >> 4, l16 = lane & 15;

  int srow = wvx * 32 + (lane >> 2);
  int scol = (lane & 3) * 8;
  const __hip_bfloat16* gA0 = A  + (size_t)(m0 + srow) * 512 + scol;
  const __hip_bfloat16* gA1 = gA0 + (size_t)16 * 512;
  const __hip_bfloat16* gB0 = Bm + (size_t)(n0 + srow) * 512 + scol;
  const __hip_bfloat16* gB1 = gB0 + (size_t)16 * 512;

  auto stage = [&](int kk, int bsel) {
    int lb = bsel * 4096 + wvx * 1024;
    gload_lds16(gA0 + kk, &As[lb]);
    gload_lds16(gA1 + kk, &As[lb + 512]);
    gload_lds16(gB0 + kk, &Bs[lb]);
    gload_lds16(gB1 + kk, &Bs[lb + 512]);
  };

  f32x4 acc[4][4] = {};
  stage(0, 0);
  for (int kt = 0; kt < 16; kt++) {
    __syncthreads();
    if (kt + 1 < 16) stage((kt + 1) << 5, (kt + 1) & 1);
    const __hip_bfloat16* Ab = &As[(kt & 1) * 4096];
    const __hip_bfloat16* Bb = &Bs[(kt & 1) * 4096];
    bf16x8 af[4], bfr[4];
#pragma unroll
    for (int i = 0; i < 4; i++)
      af[i] = *(const bf16x8*)&Ab[(wr + i * 16 + l16) * 32 + quad * 8];
#pragma unroll
    for (int j = 0; j < 4; j++)
      bfr[j] = *(const bf16x8*)&Bb[(wc + j * 16 + l16) * 32 + quad * 8];
#pragma unroll
    for (int i = 0; i < 4; i++)
#pragma unroll
      for (int j = 0; j < 4; j++)
        acc[i][j] = __builtin_amdgcn_mfma_f32_16x16x32_bf16(af[i], bfr[j],
                                                            acc[i][j], 0, 0, 0);
  }

  // ---- epilogue via LDS: C-layout -> row-major coalesced ----
  float bj[4], bm[4][4];
  if (!isV) {
#pragma unroll
    for (int j = 0; j < 4; j++) bj[j] = bqk[n0 + wc + j * 16 + l16];
  } else {
#pragma unroll
    for (int i = 0; i < 4; i++)
#pragma unroll
      for (int r = 0; r < 4; r++)
        bm[i][r] = bv[m0 + wr + i * 16 + quad * 4 + r];
  }
  __syncthreads();  // dbuf fragment reads done before epi overwrite
#pragma unroll
  for (int i = 0; i < 4; i++)
#pragma unroll
    for (int j = 0; j < 4; j++)
#pragma unroll
      for (int r = 0; r < 4; r++) {
        int ml = wr + i * 16 + quad * 4 + r;
        int nl = wc + j * 16 + l16;
        float v = acc[i][j][r] + (isV ? bm[i][r] : bj[j]);
        epi[ml * 136 + nl] = __float2bfloat16(v);
      }
  __syncthreads();
  int mr = tid >> 1, h = tid & 1;
  const __hip_bfloat16* rowp = &epi[mr * 136 + h * 64];
  if (!isV) {
    __hip_bfloat16* o = qk + (size_t)(m0 + mr) * 1024 + n0 + h * 64;
#pragma unroll
    for (int c = 0; c < 8; c++)
      *(uint4*)(o + c * 8) = *(const uint4*)(rowp + c * 8);
  } else {
    int b = (n0 + h * 64) >> 12, t = (n0 + h * 64) & 4095;
    __hip_bfloat16* o = vT + ((size_t)(b * 512 + m0 + mr)) * 4096 + t;
#pragma unroll
    for (int c = 0; c < 8; c++)
      *(uint4*)(o + c * 8) = *(const uint4*)(rowp + c * 8);
  }
}

// ====== fused attention v6: wave-private staging, near-barrier-free ======
// Grid 1024 = (2b x 4spl: one group per XCD) x 128 q-tiles(32 rows). 8 waves.
// Key remap: QK kv-split 16/wave (kvc0=wv*16) and PV d-split 64/wave
// (wd0=wv*64) make K and V staging WAVE-PRIVATE: each wave reads exactly the
// LDS it staged -> per-wave s_waitcnt vmcnt(N) instead of __syncthreads.
// Each wave owns a 4KB union slot: QK = ring-4 of BK=32 K stages (private,
// vmcnt(3) = 3-period prefetch distance); PV = one [64 d][32 kv] V sub-slab.
// Only 2 barriers per t: B (Ps visible before PV) and C (Ps rewrite guard).
// LDS 73K -> 2 blocks/CU. Qs persistent (one startup barrier).
__global__ __launch_bounds__(512, 4) void attn_k(
    const __hip_bfloat16* __restrict__ qk, const __hip_bfloat16* __restrict__ vT,
    __hip_bfloat16* __restrict__ part, float* __restrict__ rsum) {
  const float scale = 0.044194173824159216f;
  int bid = blockIdx.x;
  int g = bid & 7;
  int b = g >> 2, spl = g & 3;
  int qtile = bid >> 3;  // 0..127

  const __hip_bfloat16* qkb = qk + (size_t)b * 4194304;
  const __hip_bfloat16* vTb = vT + (size_t)b * 2097152;

  __shared__ __align__(16) unsigned char smem[74752];
  __hip_bfloat16* Qs = (__hip_bfloat16*)smem;             // [32][512] swz 32K
  // union [32K,64K): per-wave 4KB slot = K ring-4 (QK) | V slab (PV)
  __hip_bfloat16* Ps = (__hip_bfloat16*)(smem + 65536);   // [32][128] swz 8K
  float* Rs = (float*)(smem + 73728);                     // [8][32] 1K

  int tid = threadIdx.x, wv = tid >> 6, lane = tid & 63;
  int quad = lane >> 4, l16 = lane & 15;
  int kvc0 = wv * 16;  // QK: wave kv-cols; PV: wave d-cols = wv*64

  __hip_bfloat16* slot = (__hip_bfloat16*)(smem + 32768 + wv * 4096);

  // ---- persistent Q: LDS[r][chunk c] = G[r][c ^ (r&7)] (16B chunks) ----
#pragma unroll
  for (int i = 0; i < 4; i++) {
    int r = wv * 4 + i;
    gload_lds16(qkb + (size_t)(qtile * 32 + r) * 1024 + (lane ^ (r & 7)) * 8,
                &Qs[r * 512]);
  }

  // K private staging: stage s = [16 kv (wave's)][32 d], 1 inst, ring slot s&3
  // LDS[row][chunk] = G[row][chunk ^ (row&3)] (16B chunks within 64B row)
  const __hip_bfloat16* gKw =
      qkb + (size_t)(spl * 1024 + wv * 16 + (lane >> 2)) * 1024 + 512 +
      ((lane & 3) ^ ((lane >> 2) & 3)) * 8;
  auto stageK32 = [&](int t, int s) {
    gload_lds16(gKw + (size_t)t * 131072 + s * 32, slot + (s & 3) * 512);
  };

  // V private staging: [64 d (wave's)][32 kv] slab, 4 insts, same swizzle
  const __hip_bfloat16* gVw =
      vTb + (size_t)(wv * 64 + (lane >> 2)) * 4096 + spl * 1024 +
      ((lane & 3) ^ ((lane >> 2) & 3)) * 8;
  auto stageVp = [&](int t, int sub) {
#pragma unroll
    for (int c = 0; c < 4; c++)
      gload_lds16(gVw + (size_t)t * 128 + sub * 32 + (size_t)(c * 16) * 4096,
                  slot + c * 512);
  };

  f32x4 accS[2] = {};
  f32x4 accO[2][4] = {};
  float rsr[8] = {};

  stageK32(0, 0);
  stageK32(0, 1);
  stageK32(0, 2);
  // own Q landed (oldest 4 of 7); startup barrier makes Qs visible block-wide
  asm volatile("s_waitcnt vmcnt(3)" ::: "memory");
  __builtin_amdgcn_s_barrier();
  asm volatile("" ::: "memory");

  for (int t = 0; t < 8; t++) {
    // ---- QK^T: 16 private BK=32 stages, ring-4, zero barriers ----
#pragma unroll
    for (int s = 0; s < 16; s++) {
      if (s < 13) {
        stageK32(t, s + 3);
        // <=3 outstanding => 4th-newest (stage s) landed
        asm volatile("s_waitcnt vmcnt(3)" ::: "memory");
      } else if (s == 13) {
        asm volatile("s_waitcnt vmcnt(2)" ::: "memory");
      } else if (s == 14) {
        asm volatile("s_waitcnt vmcnt(1)" ::: "memory");
      } else {
        asm volatile("s_waitcnt vmcnt(0)" ::: "memory");
      }
      const __hip_bfloat16* Kb = slot + (s & 3) * 512;
      int rk = kvc0 + l16;
      (void)rk;
      bf16x8 bk = *(const bf16x8*)&Kb[l16 * 32 + ((quad ^ (l16 & 3)) << 3)];
#pragma unroll
      for (int qg = 0; qg < 2; qg++) {
        int rq = qg * 16 + l16;
        bf16x8 aq = *(const bf16x8*)
            &Qs[rq * 512 + (((s * 4 + quad) ^ (rq & 7)) << 3)];
        accS[qg] = __builtin_amdgcn_mfma_f32_16x16x32_bf16(aq, bk, accS[qg],
                                                           0, 0, 0);
      }
    }
    // own K reads retired -> own slot free for V(0); DMA hides under exp+B
    asm volatile("s_waitcnt lgkmcnt(0)" ::: "memory");
    stageVp(t, 0);
    // ---- exp + rowsum, P -> swizzled Ps[32][128] ----
#pragma unroll
    for (int qg = 0; qg < 2; qg++) {
#pragma unroll
      for (int rr = 0; rr < 4; rr++) {
        float p = __expf(accS[qg][rr] * scale);
        rsr[qg * 4 + rr] += p;
        int row = qg * 16 + quad * 4 + rr;
        int col = kvc0 + l16;
        Ps[row * 128 + (((col >> 3) ^ (row & 7)) << 3) + (col & 7)] =
            __float2bfloat16(p);
      }
      accS[qg] = (f32x4){0.f, 0.f, 0.f, 0.f};
    }
    // barrier B: Ps visible to all waves (raw: V(0) stays in flight)
    asm volatile("s_waitcnt lgkmcnt(0)" ::: "memory");
    __builtin_amdgcn_s_barrier();
    asm volatile("" ::: "memory");
    // ---- PV: 4 private V subs; per-wave vmcnt waits, zero barriers ----
#pragma unroll
    for (int sub = 0; sub < 4; sub++) {
      asm volatile("s_waitcnt vmcnt(0)" ::: "memory");
      bf16x8 pa[2], bvf[4];
#pragma unroll
      for (int qg = 0; qg < 2; qg++) {
        int rq = qg * 16 + l16;
        pa[qg] = *(const bf16x8*)
            &Ps[rq * 128 + (((sub * 4 + quad) ^ (rq & 7)) << 3)];
      }
#pragma unroll
      for (int dj = 0; dj < 4; dj++)
        bvf[dj] = *(const bf16x8*)
            &slot[(dj * 16 + l16) * 32 + ((quad ^ (l16 & 3)) << 3)];
      // frags in regs -> own slot free for next sub (rule-18 fence)
      asm volatile("s_waitcnt lgkmcnt(0)" ::: "memory");
      __builtin_amdgcn_sched_barrier(0);
      if (sub < 3) stageVp(t, sub + 1);
#pragma unroll
      for (int dj = 0; dj < 4; dj++)
#pragma unroll
        for (int qg = 0; qg < 2; qg++)
          accO[qg][dj] = __builtin_amdgcn_mfma_f32_16x16x32_bf16(
              pa[qg], bvf[dj], accO[qg][dj], 0, 0, 0);
    }
    // barrier C: all PV Ps-reads done before next-t exp rewrites Ps
    asm volatile("" ::: "memory");
    __builtin_amdgcn_s_barrier();
    asm volatile("" ::: "memory");
    if (t + 1 < 8) {
      stageK32(t + 1, 0);
      stageK32(t + 1, 1);
      stageK32(t + 1, 2);
    }
  }

  // ---- epilogue: partials (bf16) + per-row expsum ----
  size_t pbase = ((size_t)(spl * 2 + b) * 4096 + qtile * 32) * 512;
#pragma unroll
  for (int qg = 0; qg < 2; qg++)
#pragma unroll
    for (int rr = 0; rr < 4; rr++) {
      int row = qg * 16 + quad * 4 + rr;
#pragma unroll
      for (int dj = 0; dj < 4; dj++)
        part[pbase + (size_t)row * 512 + wv * 64 + dj * 16 + l16] =
            __float2bfloat16(accO[qg][dj][rr]);
    }
#pragma unroll
  for (int k = 0; k < 8; k++)
#pragma unroll
    for (int off = 1; off < 16; off <<= 1) rsr[k] += __shfl_xor(rsr[k], off);
  if (l16 == 0) {
#pragma unroll
    for (int qg = 0; qg < 2; qg++)
#pragma unroll
      for (int rr = 0; rr < 4; rr++)
        Rs[wv * 32 + qg * 16 + quad * 4 + rr] = rsr[qg * 4 + rr];
  }
  __syncthreads();
  if (tid < 32) {
    float s = 0.f;
#pragma unroll
    for (int w = 0; w < 8; w++) s += Rs[w * 32 + tid];
    rsum[spl * 8192 + b * 4096 + qtile * 32 + tid] = s;
  }
}

// ---- fold 4 kv-split partials + expsums, normalize -> obuf ----
__global__ __launch_bounds__(256) void reduce2_k(
    const __hip_bfloat16* __restrict__ part, const float* __restrict__ rsum,
    __hip_bfloat16* __restrict__ obuf) {
  size_t i8 = (size_t)blockIdx.x * 256 + threadIdx.x;
  size_t perb = 262144;  // 4096*512/8 vectors per batch
  size_t b = i8 / perb, r = i8 - b * perb;
  int t = (int)(r >> 6);
  float ps = rsum[b * 4096 + t] + rsum[8192 + b * 4096 + t] +
             rsum[16384 + b * 4096 + t] + rsum[24576 + b * 4096 + t];
  float inv = 1.f / ps;
  float acc[8] = {};
#pragma unroll
  for (int sp = 0; sp < 4; sp++) {
    bf16x8 v = ((const bf16x8*)part)[(sp * 2 + b) * perb + r];
#pragma unroll
    for (int l = 0; l < 8; l++) acc[l] += (float)v[l];
  }
  bf16x8 o;
#pragma unroll
  for (int l = 0; l < 8; l++) o[l] = (__bf16)(acc[l] * inv);
  ((bf16x8*)obuf)[b * perb + r] = o;
}

// ====== out-proj, 64x128 tiles (512 blocks = 2/CU vs old 256 = 1/CU) ======
// out[b][c][t] = x[b][c][t] + bf16(sum_o Wo[c][o]*obuf[b][t][o] + bo[c])
__global__ __launch_bounds__(256, 2) void oproj_k(
    const __hip_bfloat16* __restrict__ Wo, const __hip_bfloat16* __restrict__ O,
    float* __restrict__ out, const float* __restrict__ bias,
    const float* __restrict__ resid) {
  int m0 = blockIdx.y * 64, n0 = blockIdx.x * 128, bb = blockIdx.z;
  O += (size_t)bb * 4096 * 512;
  size_t cbase = (size_t)bb * 512 * 4096;

  __shared__ __align__(16) unsigned char smem[24576];  // A 2x4K | B 2x8K; epi
  __hip_bfloat16* As  = (__hip_bfloat16*)smem;          // 2 x [64][32]
  __hip_bfloat16* Bs  = As + 4096;                      // 2 x [128][32]
  __hip_bfloat16* epi = (__hip_bfloat16*)smem;          // [64][136] = 17.4K

  int tid = threadIdx.x, wv = tid >> 6, lane = tid & 63;
  int wr = (wv >> 1) * 32, wc = (wv & 1) * 64;
  int quad = lane >> 4, l16 = lane & 15;

  int lr = lane >> 2, scol = (lane & 3) * 8;
  const __hip_bfloat16* gA  = Wo + (size_t)(m0 + wv * 16 + lr) * 512 + scol;
  const __hip_bfloat16* gB0 = O  + (size_t)(n0 + wv * 32 + lr) * 512 + scol;
  const __hip_bfloat16* gB1 = gB0 + (size_t)16 * 512;

  auto stage = [&](int kk, int bsel) {
    gload_lds16(gA + kk, &As[bsel * 2048 + wv * 512]);
    gload_lds16(gB0 + kk, &Bs[bsel * 4096 + wv * 1024]);
    gload_lds16(gB1 + kk, &Bs[bsel * 4096 + wv * 1024 + 512]);
  };

  f32x4 acc[2][4] = {};
  stage(0, 0);
  for (int kt = 0; kt < 16; kt++) {
    __syncthreads();
    if (kt + 1 < 16) stage((kt + 1) << 5, (kt + 1) & 1);
    const __hip_bfloat16* Ab = &As[(kt & 1) * 2048];
    const __hip_bfloat16* Bb = &Bs[(kt & 1) * 4096];
    bf16x8 af[2], bfr[4];
#pragma unroll
    for (int i = 0; i < 2; i++)
      af[i] = *(const bf16x8*)&Ab[(wr + i * 16 + l16) * 32 + quad * 8];
#pragma unroll
    for (int j = 0; j < 4; j++)
      bfr[j] = *(const bf16x8*)&Bb[(wc + j * 16 + l16) * 32 + quad * 8];
#pragma unroll
    for (int i = 0; i < 2; i++)
#pragma unroll
      for (int j = 0; j < 4; j++)
        acc[i][j] = __builtin_amdgcn_mfma_f32_16x16x32_bf16(af[i], bfr[j],
                                                            acc[i][j], 0, 0, 0);
  }

  float pre[2][4];
#pragma unroll
  for (int i = 0; i < 2; i++)
#pragma unroll
    for (int r = 0; r < 4; r++)
      pre[i][r] = bias[m0 + wr + i * 16 + quad * 4 + r];
  __syncthreads();
#pragma unroll
  for (int i = 0; i < 2; i++)
#pragma unroll
    for (int j = 0; j < 4; j++)
#pragma unroll
      for (int r = 0; r < 4; r++)
        epi[(wr + i * 16 + quad * 4 + r) * 136 + wc + j * 16 + l16] =
            __float2bfloat16(acc[i][j][r] + pre[i][r]);
  __syncthreads();
  int mr = tid >> 2, seg = tid & 3;  // 4 threads/row, 32 elems each
  const __hip_bfloat16* rowp = &epi[mr * 136 + seg * 32];
  size_t obase = cbase + (size_t)(m0 + mr) * 4096 + n0 + seg * 32;
#pragma unroll
  for (int c = 0; c < 4; c++) {
    bf16x8 val = *(const bf16x8*)(rowp + c * 8);
    size_t idx = obase + c * 8;
    float4 r0 = *(const float4*)&resid[idx];
    float4 r1 = *(const float4*)&resid[idx + 4];
    float4 o0, o1;
    o0.x = r0.x + (float)val[0]; o0.y = r0.y + (float)val[1];
    o0.z = r0.z + (float)val[2]; o0.w = r0.w + (float)val[3];
    o1.x = r1.x + (float)val[4]; o1.y = r1.y + (float)val[5];
    o1.z = r1.z + (float)val[6]; o1.w = r1.w + (float)val[7];
    *(float4*)&out[idx] = o0;
    *(float4*)&out[idx + 4] = o1;
  }
}

extern "C" void kernel_launch(void* const* d_in, const int* in_sizes, int n_in,
                              void* d_out, int out_size, void* d_ws,
                              size_t ws_size, hipStream_t stream) {
  const float* xp  = (const float*)d_in[0];
  const float* gwp = (const float*)d_in[1];
  const float* gbp = (const float*)d_in[2];
  const float* wqp = (const float*)d_in[3];
  const float* bqp = (const float*)d_in[4];
  const float* wkp = (const float*)d_in[5];
  const float* bkp = (const float*)d_in[6];
  const float* wvp = (const float*)d_in[7];
  const float* bvp = (const float*)d_in[8];
  const float* wop = (const float*)d_in[9];
  const float* bop = (const float*)d_in[10];
  float* outp = (float*)d_out;

  char* w = (char*)d_ws;
  size_t off = 0;
  auto alloc = [&](size_t bytes) {
    void* p = w + off;
    off += (bytes + 255) & ~(size_t)255;
    return p;
  };
  float* stats         = (float*)alloc(64 * 2 * sizeof(float));
  __hip_bfloat16* hf   = (__hip_bfloat16*)alloc((size_t)2 * 4096 * 512 * 2);
  __hip_bfloat16* wqkb = (__hip_bfloat16*)alloc((size_t)1024 * 512 * 2);
  __hip_bfloat16* wvb  = (__hip_bfloat16*)alloc((size_t)512 * 512 * 2);
  __hip_bfloat16* wob  = (__hip_bfloat16*)alloc((size_t)512 * 512 * 2);
  float* bqk           = (float*)alloc(1024 * sizeof(float));
  float* rsum          = (float*)alloc((size_t)4 * 2 * 4096 * sizeof(float));
  __hip_bfloat16* qk   = (__hip_bfloat16*)alloc((size_t)2 * 4096 * 1024 * 2);
  __hip_bfloat16* vT   = (__hip_bfloat16*)alloc((size_t)2 * 512 * 4096 * 2);
  __hip_bfloat16* obuf = (__hip_bfloat16*)alloc((size_t)2 * 4096 * 512 * 2);
  __hip_bfloat16* part = (__hip_bfloat16*)alloc((size_t)8 * 4096 * 512 * 2);

  // prelude: 4096 cvt blocks + 64 gn_stats blocks + 1 bcat block
  prelude_k<<<4161, 256, 0, stream>>>(wqp, wkp, wvp, wop, wqkb, wvb, wob,
                                      bqp, bkp, bqk, xp, stats);

  gn_apply_k<<<dim3(8, 64, 2), 256, 0, stream>>>(xp, stats, gwp, gbp, hf);

  // fused QKV: qk[8192][1024] and vT[2][512][4096]
  qkv_k<<<dim3(12, 64, 1), 256, 0, stream>>>(hf, wqkb, wvb, bqk, bvp, qk, vT);

  // fused attention v6: 1024 blocks (2/CU), wave-private staging, kv-split 4
  attn_k<<<1024, 512, 0, stream>>>(qk, vT, part, rsum);

  // fold 4 partials + expsums, normalize -> obuf
  reduce2_k<<<2048, 256, 0, stream>>>(part, rsum, obuf);

  // out[b][c][t] = x + Wo*O + bo  (64x128 tiles, 512 blocks)
  oproj_k<<<dim3(32, 8, 2), 256, 0, stream>>>(wob, obuf, outp, bop, xp);
}